// Round 10
// baseline (1993.637 us; speedup 1.0000x reference)
//
#include <hip/hip_runtime.h>
#include <hip/hip_bf16.h>
#include <cmath>

#define DD 1536
#define FF 6144

typedef __bf16 bf16_t;
typedef __bf16 bf16x8 __attribute__((ext_vector_type(8)));
typedef __bf16 bf16x4 __attribute__((ext_vector_type(4)));
typedef float  f32x4  __attribute__((ext_vector_type(4)));

#define VM6 asm volatile("s_waitcnt vmcnt(6)" ::: "memory")
#define VM0 asm volatile("s_waitcnt vmcnt(0)" ::: "memory")
#define SB  __builtin_amdgcn_sched_barrier(0)
#define LGKM_0 do { asm volatile("s_waitcnt lgkmcnt(0)" :::); SB; } while (0)
#define LGKM_4 do { asm volatile("s_waitcnt lgkmcnt(4)" :::); SB; } while (0)
#define LGKM_8 do { asm volatile("s_waitcnt lgkmcnt(8)" :::); SB; } while (0)
#define BAR __builtin_amdgcn_s_barrier()

__device__ __forceinline__ void async_load16(const bf16_t* g, bf16_t* l) {
  __builtin_amdgcn_global_load_lds(
      (const __attribute__((address_space(1))) void*)g,
      (__attribute__((address_space(3))) void*)l, 16, 0, 0);
}

// inline-asm LDS read: NOT ordered vs global_load_lds by the compiler; ordering is
// done explicitly via {vmcnt; barrier} (RAW) and counted lgkmcnt + sched_barrier (use).
__device__ __forceinline__ bf16x8 ds_read128(unsigned int addr) {
  bf16x8 r;
  asm volatile("ds_read_b128 %0, %1" : "=v"(r) : "v"(addr));
  return r;
}

// bijective XCD-aware remap (m204)
__device__ __forceinline__ void xcd_remap(int& bx, int& by) {
  const int gx = gridDim.x, gy = gridDim.y;
  int wg = by * gx + bx;
  const int nwg = gx * gy;
  const int q = nwg >> 3, r = nwg & 7, xcd = wg & 7, o = wg >> 3;
  wg = (xcd < r ? xcd * (q + 1) : r * (q + 1) + (xcd - r) * q) + o;
  bx = wg % gx;
  by = wg / gx;
}

// ---------------- weight fp32 -> bf16 transpose; optional per-K scale; output row stride ldt
__global__ __launch_bounds__(256) void transpose_to_bf16(
    const float* __restrict__ W, bf16_t* __restrict__ Wt, int K, int N,
    const float* __restrict__ s, int ldt) {
  __shared__ float tile[32][33];
  const int tx = threadIdx.x, ty = threadIdx.y;  // 32 x 8
  const int n0 = blockIdx.x * 32, k0 = blockIdx.y * 32;
#pragma unroll
  for (int i = 0; i < 4; i++)
    tile[ty + 8 * i][tx] = W[(size_t)(k0 + ty + 8 * i) * N + n0 + tx];
  __syncthreads();
  const float sc = (s != nullptr) ? s[k0 + tx] : 1.f;
#pragma unroll
  for (int i = 0; i < 4; i++)
    Wt[(size_t)(n0 + ty + 8 * i) * ldt + k0 + tx] = (bf16_t)(tile[tx][ty + 8 * i] * sc);
}

// ---------------- biasm = a + b ----------------
__global__ __launch_bounds__(256) void bias_add2(
    const float* __restrict__ a, const float* __restrict__ b, float* __restrict__ o, int n) {
  const int i = blockIdx.x * 256 + threadIdx.x;
  if (i < n) o[i] = a[i] + b[i];
}

// ---------------- reduction helpers ----------------
__device__ __forceinline__ void breduce1(float& a) {
#pragma unroll
  for (int off = 32; off; off >>= 1) a += __shfl_xor(a, off);
  __shared__ float sa[4];
  const int w = threadIdx.x >> 6, ln = threadIdx.x & 63;
  if (ln == 0) sa[w] = a;
  __syncthreads();
  a = (sa[0] + sa[1]) + (sa[2] + sa[3]);
  __syncthreads();
}

__device__ __forceinline__ void breduce2(float& a, float& b) {
#pragma unroll
  for (int off = 32; off; off >>= 1) {
    a += __shfl_xor(a, off);
    b += __shfl_xor(b, off);
  }
  __shared__ float sa[4], sb[4];
  const int w = threadIdx.x >> 6, ln = threadIdx.x & 63;
  if (ln == 0) { sa[w] = a; sb[w] = b; }
  __syncthreads();
  a = (sa[0] + sa[1]) + (sa[2] + sa[3]);
  b = (sb[0] + sb[1]) + (sb[2] + sb[3]);
  __syncthreads();
}

// ---------------- x: shared rms factor -> xr = x*rq (bf16), xb = x (bf16) ----------------
__global__ __launch_bounds__(256) void norm_x2(
    const float* __restrict__ x, bf16_t* __restrict__ xr, bf16_t* __restrict__ xb) {
  const int row = blockIdx.x, t = threadIdx.x;
  const float* p = x + (size_t)row * DD;
  f32x4 v0 = ((const f32x4*)p)[t];
  f32x4 v1 = 0.0f;
  if (t < 128) v1 = ((const f32x4*)p)[256 + t];
  float s2 = 0.f;
#pragma unroll
  for (int e = 0; e < 4; e++) s2 += v0[e] * v0[e];
  if (t < 128) {
#pragma unroll
    for (int e = 0; e < 4; e++) s2 += v1[e] * v1[e];
  }
  breduce1(s2);
  const float rq = rsqrtf(s2 * (1.f / DD) + 1e-7f);
  auto emit = [&](int ci, f32x4 v) {
    bf16x4 orr, ob;
#pragma unroll
    for (int e = 0; e < 4; e++) {
      orr[e] = (bf16_t)(v[e] * rq);
      ob[e] = (bf16_t)v[e];
    }
    const size_t o = (size_t)row * DD + ci * 4;
    *(bf16x4*)(xr + o) = orr;
    *(bf16x4*)(xb + o) = ob;
  };
  emit(t, v0);
  if (t < 128) emit(256 + t, v1);
}

// ---------------- LayerNorm -> bf16 ----------------
__global__ __launch_bounds__(256) void norm_ln(
    const float* __restrict__ x, const float* __restrict__ w,
    const float* __restrict__ bb, bf16_t* __restrict__ o) {
  const int row = blockIdx.x, t = threadIdx.x;
  const float* p = x + (size_t)row * DD;
  f32x4 v0 = ((const f32x4*)p)[t];
  f32x4 v1 = 0.0f;
  if (t < 128) v1 = ((const f32x4*)p)[256 + t];
  float s = 0.f, s2 = 0.f;
#pragma unroll
  for (int e = 0; e < 4; e++) { s += v0[e]; s2 += v0[e] * v0[e]; }
  if (t < 128) {
#pragma unroll
    for (int e = 0; e < 4; e++) { s += v1[e]; s2 += v1[e] * v1[e]; }
  }
  breduce2(s, s2);
  const float mu = s * (1.f / DD);
  const float rln = rsqrtf(s2 * (1.f / DD) - mu * mu + 1e-5f);
  auto emit = [&](int ci, f32x4 v) {
    const int i0 = ci * 4;
    bf16x4 ov;
#pragma unroll
    for (int e = 0; e < 4; e++)
      ov[e] = (bf16_t)((v[e] - mu) * rln * w[i0 + e] + bb[i0 + e]);
    *(bf16x4*)(o + (size_t)row * DD + i0) = ov;
  };
  emit(t, v0);
  if (t < 128) emit(256 + t, v1);
}

// ---------------- text: Tb = raw bf16, Tck = text*rtq ----------
__global__ __launch_bounds__(256) void norm_t2(
    const float* __restrict__ te, bf16_t* __restrict__ tb, bf16_t* __restrict__ tck) {
  const int row = blockIdx.x, t = threadIdx.x;
  const float* p = te + (size_t)row * DD;
  f32x4 v0 = ((const f32x4*)p)[t];
  f32x4 v1 = 0.0f;
  if (t < 128) v1 = ((const f32x4*)p)[256 + t];
  float s2 = 0.f;
#pragma unroll
  for (int e = 0; e < 4; e++) s2 += v0[e] * v0[e];
  if (t < 128) {
#pragma unroll
    for (int e = 0; e < 4; e++) s2 += v1[e] * v1[e];
  }
  breduce1(s2);
  const float rq = rsqrtf(s2 * (1.f / DD) + 1e-7f);
  auto emit = [&](int ci, f32x4 v) {
    bf16x4 ob, oc;
#pragma unroll
    for (int e = 0; e < 4; e++) {
      ob[e] = (bf16_t)v[e];
      oc[e] = (bf16_t)(v[e] * rq);
    }
    const size_t o = (size_t)row * DD + ci * 4;
    *(bf16x4*)(tb + o) = ob;
    *(bf16x4*)(tck + o) = oc;
  };
  emit(t, v0);
  if (t < 128) emit(256 + t, v1);
}

// ---------------- in-place bf16 row softmax ----------------
template <int NC>
__global__ __launch_bounds__(256) void softmax_bf16(bf16_t* __restrict__ S) {
  const int t = threadIdx.x;
  bf16_t* sr = S + (size_t)blockIdx.x * NC;
  constexpr int NV = (NC / 8 + 255) / 256;
  float v[NV][8];
  float mx = -3.4e38f;
#pragma unroll
  for (int i = 0; i < NV; i++) {
    const int idx = t + i * 256;
    if (idx * 8 < NC) {
      bf16x8 b = ((const bf16x8*)sr)[idx];
#pragma unroll
      for (int e = 0; e < 8; e++) {
        v[i][e] = (float)b[e];
        mx = fmaxf(mx, v[i][e]);
      }
    }
  }
#pragma unroll
  for (int off = 32; off; off >>= 1) mx = fmaxf(mx, __shfl_xor(mx, off));
  __shared__ float sm[4];
  const int w = t >> 6, ln = t & 63;
  if (ln == 0) sm[w] = mx;
  __syncthreads();
  mx = fmaxf(fmaxf(sm[0], sm[1]), fmaxf(sm[2], sm[3]));
  __syncthreads();
  float sum = 0.f;
#pragma unroll
  for (int i = 0; i < NV; i++) {
    const int idx = t + i * 256;
    if (idx * 8 < NC) {
#pragma unroll
      for (int e = 0; e < 8; e++) {
        v[i][e] = __expf(v[i][e] - mx);
        sum += v[i][e];
      }
    }
  }
#pragma unroll
  for (int off = 32; off; off >>= 1) sum += __shfl_xor(sum, off);
  __shared__ float ss[4];
  if (ln == 0) ss[w] = sum;
  __syncthreads();
  sum = (ss[0] + ss[1]) + (ss[2] + ss[3]);
  const float inv = 1.f / sum;
#pragma unroll
  for (int i = 0; i < NV; i++) {
    const int idx = t + i * 256;
    if (idx * 8 < NC) {
      bf16x8 o;
#pragma unroll
      for (int e = 0; e < 8; e++) o[e] = (bf16_t)(v[i][e] * inv);
      ((bf16x8*)sr)[idx] = o;
    }
  }
}

enum { EPI_BF16 = 0, EPI_F32_SCALE = 1, EPI_ADD_X = 2, EPI_ACC = 3, EPI_GELU = 4, EPI_TRANS = 5, EPI_BF16S = 6 };

template <int EPI>
__device__ __forceinline__ void epi_frag(
    f32x4 v, int r0, int c, const float* bias, void* Cout, const float* Xres,
    int ldc, float scale, int t_ld, int t_bshift, size_t t_bstride) {
  const float bv = (bias != nullptr) ? bias[c] : 0.f;
  if constexpr (EPI == EPI_BF16) {
    bf16_t* C = (bf16_t*)Cout;
#pragma unroll
    for (int r = 0; r < 4; r++) C[(size_t)(r0 + r) * ldc + c] = (bf16_t)(v[r] + bv);
  } else if constexpr (EPI == EPI_F32_SCALE) {
    float* C = (float*)Cout;
#pragma unroll
    for (int r = 0; r < 4; r++) C[(size_t)(r0 + r) * ldc + c] = v[r] * scale;
  } else if constexpr (EPI == EPI_BF16S) {
    bf16_t* C = (bf16_t*)Cout;
#pragma unroll
    for (int r = 0; r < 4; r++) C[(size_t)(r0 + r) * ldc + c] = (bf16_t)(v[r] * scale);
  } else if constexpr (EPI == EPI_ADD_X) {
    float* C = (float*)Cout;
#pragma unroll
    for (int r = 0; r < 4; r++) {
      const size_t ix = (size_t)(r0 + r) * ldc + c;
      C[ix] = Xres[ix] + v[r] + bv;
    }
  } else if constexpr (EPI == EPI_ACC) {
    float* C = (float*)Cout;
#pragma unroll
    for (int r = 0; r < 4; r++) {
      const size_t ix = (size_t)(r0 + r) * ldc + c;
      C[ix] += v[r] + bv;
    }
  } else if constexpr (EPI == EPI_GELU) {
    bf16_t* C = (bf16_t*)Cout;
#pragma unroll
    for (int r = 0; r < 4; r++) {
      const float h = v[r] + bv;
      C[(size_t)(r0 + r) * ldc + c] = (bf16_t)(0.5f * h * (1.f + erff(h * 0.70710678118654752f)));
    }
  } else {  // EPI_TRANS: batched C^T: out[b][c][n]
    const int b = r0 >> t_bshift;
    const int n = r0 & ((1 << t_bshift) - 1);
    bf16_t* C = (bf16_t*)Cout + (size_t)b * t_bstride + (size_t)c * t_ld + n;
    bf16x4 o;
#pragma unroll
    for (int r = 0; r < 4; r++) o[r] = (bf16_t)(v[r] + bv);
    *(bf16x4*)C = o;
  }
}

// ---------------- gemm_bt: 128x128 tile, 4 waves, BK=32 (proven r2 kernel + batch-B) ------
template <int EPI>
__global__ __launch_bounds__(256) void gemm_bt(
    const bf16_t* __restrict__ A, const bf16_t* __restrict__ B,
    const float* __restrict__ bias, void* __restrict__ Cout,
    const float* __restrict__ Xres,
    int nK, int lda, int ldb, int ldc, float scale,
    int bsh, size_t bstr, int t_ld, int t_bshift, size_t t_bstride) {
  __shared__ __align__(16) bf16_t As[2][128 * 32];
  __shared__ __align__(16) bf16_t Bs[2][128 * 32];
  const int tid = threadIdx.x;
  int bx = blockIdx.x, by = blockIdx.y;
  xcd_remap(bx, by);
  const int m0 = by * 128, n0 = bx * 128;
  const int wave = tid >> 6, lane = tid & 63, l15 = lane & 15, hi = lane >> 4;
  const int wm = wave >> 1, wn = wave & 1;
  const int srow = tid >> 2, scol = (tid & 3) << 3;

  const bf16_t* Bb = bsh ? (B + (size_t)(m0 >> bsh) * bstr) : B;
  const bf16_t* ga = A + (size_t)(m0 + srow) * lda + scol;
  const bf16_t* gb = Bb + (size_t)(n0 + srow) * ldb + scol;
  const int lo = wave * 512;

  f32x4 acc[4][4];
#pragma unroll
  for (int i = 0; i < 4; i++)
#pragma unroll
    for (int j = 0; j < 4; j++) acc[i][j] = 0.0f;

  auto stage = [&](int buf, int kt) {
    const bf16_t* a = ga + (size_t)kt * 32;
    const bf16_t* b = gb + (size_t)kt * 32;
    async_load16(a, &As[buf][lo]);
    async_load16(a + (size_t)64 * lda, &As[buf][2048 + lo]);
    async_load16(b, &Bs[buf][lo]);
    async_load16(b + (size_t)64 * ldb, &Bs[buf][2048 + lo]);
  };

  auto compute = [&](int buf) {
    bf16x8 af[4], bg[4];
#pragma unroll
    for (int i = 0; i < 4; i++)
      af[i] = *(const bf16x8*)&As[buf][(wm * 64 + i * 16 + l15) * 32 + hi * 8];
#pragma unroll
    for (int j = 0; j < 4; j++)
      bg[j] = *(const bf16x8*)&Bs[buf][(wn * 64 + j * 16 + l15) * 32 + hi * 8];
#pragma unroll
    for (int i = 0; i < 4; i++)
#pragma unroll
      for (int j = 0; j < 4; j++)
        acc[i][j] = __builtin_amdgcn_mfma_f32_16x16x32_bf16(af[i], bg[j], acc[i][j], 0, 0, 0);
  };

  stage(0, 0);
  __syncthreads();
  for (int kt = 0; kt < nK; ++kt) {
    if (kt + 1 < nK) stage((kt + 1) & 1, kt + 1);
    compute(kt & 1);
    __syncthreads();
  }

#pragma unroll
  for (int i = 0; i < 4; i++) {
    const int r0 = m0 + wm * 64 + i * 16 + hi * 4;
#pragma unroll
    for (int j = 0; j < 4; j++) {
      const int c = n0 + wn * 64 + j * 16 + l15;
      epi_frag<EPI>(acc[i][j], r0, c, bias, Cout, Xres, ldc, scale, t_ld, t_bshift, t_bstride);
    }
  }
}

// ---------------- gemm8: 256x256, 8 waves, BK=64, reg-fragment one-phase-ahead pipeline ----
// Fragments double-buffered in registers (af0/af1, bg0/bg1); each phase issues NEXT
// quadrant's ds_reads, then a COUNTED lgkmcnt for the current operands (issued a full
// phase earlier -> wait ~free). FIFO lgkm ledger: q0 issues bg1(4) -> lgkm(4) drains
// af0+bg0 (12 from prior q3); q1 issues af1(8) -> lgkm(8) drains bg1; q2 -> lgkm(0)
// drains af1; q3 {stg; VM6; BAR} confirms tile k+1, then reads af0/bg0[nbuf] (after
// the globalizing barrier - r6 lesson), MM(1,1) needs no wait. vmcnt ledger identical
// to r9 (6 newest at q3 = {Bl,Bh,Al}(k+2); VM0 on tails). WAR: Bs[buf] reads done by
// q1's lgkm(8)+BAR before stgB@q2; As[buf] by q2's lgkm(0)+BAR before stgA@q3;
// As/Bs[nbuf] writes 2+ barriers past their last readers (k-1's q1/q3).
template <int EPI>
__global__ __launch_bounds__(512, 2) void gemm8(
    const bf16_t* __restrict__ A, const bf16_t* __restrict__ B,
    const float* __restrict__ bias, void* __restrict__ Cout,
    const float* __restrict__ Xres,
    int nT, int lda, int ldb, int ldc, float scale,
    int bsh, size_t bstr, int t_ld, int t_bshift, size_t t_bstride) {
  __shared__ __align__(16) bf16_t As[2][256 * 64];
  __shared__ __align__(16) bf16_t Bs[2][256 * 64];
  const int tid = threadIdx.x;
  int bx = blockIdx.x, by = blockIdx.y;
  xcd_remap(bx, by);
  const int m0 = by * 256, n0 = bx * 256;
  const int wave = tid >> 6, lane = tid & 63, l15 = lane & 15, hi = lane >> 4;
  const int wm = wave >> 2, wn = wave & 3;  // 2 x 4 waves; per-wave 128x64 output

  const int srow = tid >> 3;
  const int scol = ((tid & 7) ^ (srow & 7)) << 3;
  const bf16_t* Bb = bsh ? (B + (size_t)(m0 >> bsh) * bstr) : B;
  const bf16_t* gA = A + (size_t)(m0 + srow) * lda + scol;
  const bf16_t* gB = Bb + (size_t)(n0 + srow) * ldb + scol;
  const int ldst = wave * 512;

  f32x4 acc[8][4];
#pragma unroll
  for (int i = 0; i < 8; i++)
#pragma unroll
    for (int j = 0; j < 4; j++) acc[i][j] = 0.0f;

  auto stgA = [&](int t, int half) {
    if (t >= nT) return;
    const int buf = t & 1, r0 = half << 7;
    const size_t kof = (size_t)t * 64;
    async_load16(gA + (size_t)r0 * lda + kof, &As[buf][r0 * 64 + ldst]);
    async_load16(gA + (size_t)(r0 + 64) * lda + kof, &As[buf][(r0 + 64) * 64 + ldst]);
  };
  auto stgB = [&](int t, int half) {
    if (t >= nT) return;
    const int buf = t & 1, r0 = half << 7;
    const size_t kof = (size_t)t * 64;
    async_load16(gB + (size_t)r0 * ldb + kof, &Bs[buf][r0 * 64 + ldst]);
    async_load16(gB + (size_t)(r0 + 64) * ldb + kof, &Bs[buf][(r0 + 64) * 64 + ldst]);
  };

  bf16x8 af0[4][2], af1[4][2], bg0[2][2], bg1[2][2];
  auto LDAf = [&](bf16x8 (&dst)[4][2], int buf, int mh) {
#pragma unroll
    for (int i = 0; i < 4; i++) {
      const int r = wm * 128 + (mh * 4 + i) * 16 + l15;
      const int rx = r & 7;
#pragma unroll
      for (int ks = 0; ks < 2; ks++)
        dst[i][ks] = ds_read128((unsigned int)(size_t)&As[buf][r * 64 + (((hi + 4 * ks) ^ rx) << 3)]);
    }
  };
  auto LDBf = [&](bf16x8 (&dst)[2][2], int buf, int nh) {
#pragma unroll
    for (int j = 0; j < 2; j++) {
      const int r = wn * 64 + (nh * 2 + j) * 16 + l15;
      const int rx = r & 7;
#pragma unroll
      for (int ks = 0; ks < 2; ks++)
        dst[j][ks] = ds_read128((unsigned int)(size_t)&Bs[buf][r * 64 + (((hi + 4 * ks) ^ rx) << 3)]);
    }
  };
  auto MM = [&](bf16x8 (&a)[4][2], bf16x8 (&b)[2][2], int mh, int nh) {
    __builtin_amdgcn_s_setprio(1);
#pragma unroll
    for (int i = 0; i < 4; i++)
#pragma unroll
      for (int j = 0; j < 2; j++)
#pragma unroll
        for (int ks = 0; ks < 2; ks++)
          acc[mh * 4 + i][nh * 2 + j] = __builtin_amdgcn_mfma_f32_16x16x32_bf16(
              a[i][ks], b[j][ks], acc[mh * 4 + i][nh * 2 + j], 0, 0, 0);
    __builtin_amdgcn_s_setprio(0);
  };

  // prologue: tile0 fully + tile1 {Bl,Bh,Al}; confirm tile 0 (6 newer loads in flight);
  // then pre-read tile 0's q0 operands.
  stgB(0, 0); stgB(0, 1); stgA(0, 0); stgA(0, 1);
  stgB(1, 0); stgB(1, 1); stgA(1, 0);
  if (nT > 1) { VM6; } else { VM0; }
  BAR;
  LDAf(af0, 0, 0);
  LDBf(bg0, 0, 0);
  SB;

  for (int k = 0; k < nT; ++k) {
    const int buf = k & 1;
    // q0: stage Ah(k+1); issue bg1; wait af0,bg0 (counted); MM(0,0)
    stgA(k + 1, 1);
    LDBf(bg1, buf, 1);
    SB;
    LGKM_4;
    MM(af0, bg0, 0, 0);
    BAR;
    // q1: issue af1; wait bg1 (counted); MM(0,1).  Bs[buf] reads all complete here.
    LDAf(af1, buf, 1);
    SB;
    LGKM_8;
    MM(af0, bg1, 0, 1);
    BAR;
    // q2: stage Bl(k+2); wait af1; MM(1,0).  As[buf] reads all complete here.
    stgB(k + 2, 0);
    LGKM_0;
    MM(af1, bg0, 1, 0);
    BAR;
    // q3: stage Bh,Al(k+2); confirm tile k+1; read its q0 operands; MM(1,1) (no wait).
    stgB(k + 2, 1);
    stgA(k + 2, 0);
    if (k + 2 < nT) { VM6; } else { VM0; }
    BAR;
    if (k + 1 < nT) {
      LDAf(af0, buf ^ 1, 0);
      LDBf(bg0, buf ^ 1, 0);
    }
    SB;
    MM(af1, bg1, 1, 1);
    BAR;
  }

#pragma unroll
  for (int fi = 0; fi < 8; fi++) {
    const int r0 = m0 + wm * 128 + fi * 16 + hi * 4;
#pragma unroll
    for (int fj = 0; fj < 4; fj++) {
      const int c = n0 + wn * 64 + fj * 16 + l15;
      epi_frag<EPI>(acc[fi][fj], r0, c, bias, Cout, Xres, ldc, scale, t_ld, t_bshift, t_bstride);
    }
  }
}

// ---------------- host ----------------
extern "C" void kernel_launch(void* const* d_in, const int* in_sizes, int n_in,
                              void* d_out, int out_size, void* d_ws, size_t ws_size,
                              hipStream_t stream) {
  (void)in_sizes; (void)n_in; (void)out_size; (void)ws_size;
  const float* x   = (const float*)d_in[0];
  const float* te  = (const float*)d_in[1];
  const float* sqw = (const float*)d_in[2];
  const float* skw = (const float*)d_in[3];
  const float* cqw = (const float*)d_in[4];
  const float* ckw = (const float*)d_in[5];
  const float* lnw = (const float*)d_in[6];
  const float* lnb = (const float*)d_in[7];
  const float* Wq = (const float*)d_in[8];  const float* bq = (const float*)d_in[9];
  const float* Wk = (const float*)d_in[10]; const float* bk = (const float*)d_in[11];
  const float* Wv = (const float*)d_in[12]; const float* bv = (const float*)d_in[13];
  const float* Wo = (const float*)d_in[14]; const float* bo = (const float*)d_in[15];
  const float* CWq = (const float*)d_in[16]; const float* Cbq = (const float*)d_in[17];
  const float* CWk = (const float*)d_in[18]; const float* Cbk = (const float*)d_in[19];
  const float* CWv = (const float*)d_in[20]; const float* Cbv = (const float*)d_in[21];
  const float* CWo = (const float*)d_in[22]; const float* Cbo = (const float*)d_in[23];
  const float* W1 = (const float*)d_in[24]; const float* b1 = (const float*)d_in[25];
  const float* W2 = (const float*)d_in[26]; const float* b2 = (const float*)d_in[27];
  float* out = (float*)d_out;

  // ---- arena (bf16 el offsets); peak ~170 MB ----
  bf16_t* ws = (bf16_t*)d_ws;
  bf16_t* R0 = ws;                  // 9437184: Wv^T -> {CK,CVt,Sc} -> W1^T
  bf16_t* R1 = ws + 9437184;        // 9437184: Wq|Wk|CWq^T -> CWk/CWv^T -> WTm -> W2^T
  bf16_t* R2 = ws + 18874368;       // 12582912: xr -> LNo
  bf16_t* Tb  = ws + 31457280;      // 1572864
  bf16_t* Tck = ws + 33030144;      // 1572864
  bf16_t* R4 = ws + 34603008;       // 25165824: xb -> Q|K(ldc3072) -> concat APre|CPre -> H[0:..]
  bf16_t* R5 = ws + 59768832;       // 12582912: V^T -> H mid
  bf16_t* R6 = ws + 72351744;       // 12582912: CQ -> H end
  bf16_t* S  = ws;                  // 33554432 overlay (self-attn scores)
  float* biascat = (float*)(ws + 84934656);  // 3072 f32
  float* biasm   = (float*)(ws + 84940800);  // 1536 f32
  bf16_t* CK  = R0;
  bf16_t* CVt = R0 + 1572864;
  bf16_t* Sc  = R0 + 3145728;       // 8192x512 bf16
  bf16_t* H   = R4;                 // 8192x6144 (R4+R5+R6 contiguous)

  const dim3 blk(256), blk8(512), tb(32, 8);
  const float scl = 0.025515518153991442f;  // 1/sqrt(1536)

  auto T = [&](const float* W, bf16_t* Wt, int K, int N, const float* s, int ldt) {
    transpose_to_bf16<<<dim3(N / 32, K / 32), tb, 0, stream>>>(W, Wt, K, N, s, ldt);
  };
  auto g8 = [](int M, int N) { return dim3(N / 256, M / 256); };
  auto g4 = [](int M, int N) { return dim3(N / 128, M / 128); };

  // biases
  hipMemcpyAsync(biascat, bq, DD * sizeof(float), hipMemcpyDeviceToDevice, stream);
  hipMemcpyAsync(biascat + DD, bk, DD * sizeof(float), hipMemcpyDeviceToDevice, stream);
  bias_add2<<<6, blk, 0, stream>>>(bo, Cbo, biasm, DD);

  // norms for x
  norm_x2<<<8192, blk, 0, stream>>>(x, R2 /*xr*/, R4 /*xb*/);

  // V projection (raw x) -> V^T batched
  T(Wv, R0, DD, DD, nullptr, DD);
  gemm8<EPI_TRANS><<<g8(8192, DD), blk8, 0, stream>>>(R4 /*xb*/, R0, bv, R5, nullptr,
      24, DD, DD, 0, 1.f, 0, 0, 4096, 12, (size_t)DD * 4096);

  // merged Q|K projection + CQ projection (rms weights folded into W^T)
  T(Wq, R1, DD, DD, sqw, DD);
  T(Wk, R1 + 2359296, DD, DD, skw, DD);
  T(CWq, R1 + 4718592, DD, DD, cqw, DD);
  gemm8<EPI_BF16><<<g8(8192, 3072), blk8, 0, stream>>>(R2, R1, biascat, R4, nullptr,
      24, DD, DD, 3072, 1.f, 0, 0, 0, 0, 0);
  gemm8<EPI_BF16><<<g8(8192, DD), blk8, 0, stream>>>(R2, R1 + 4718592, Cbq, R6, nullptr,
      24, DD, DD, DD, 1.f, 0, 0, 0, 0, 0);

  // self-attention (batched over 2 via m0>>12)
  gemm8<EPI_BF16S><<<g8(8192, 4096), blk8, 0, stream>>>(R4 /*Q*/, R4 + DD /*K*/, nullptr, S, nullptr,
      24, 3072, 3072, 4096, scl, 12, (size_t)4096 * 3072, 0, 0, 0);
  softmax_bf16<4096><<<8192, blk, 0, stream>>>(S);
  gemm8<EPI_BF16><<<g8(8192, DD), blk8, 0, stream>>>(S, R5, nullptr, R4, nullptr,
      64, 4096, 4096, 3072, 1.f, 12, (size_t)DD * 4096, 0, 0, 0);

  // cross-attention
  norm_t2<<<1024, blk, 0, stream>>>(te, Tb, Tck);
  T(CWk, R1, DD, DD, ckw, DD);
  gemm_bt<EPI_BF16><<<g4(1024, DD), blk, 0, stream>>>(Tck, R1, Cbk, CK, nullptr,
      48, DD, DD, DD, 1.f, 0, 0, 0, 0, 0);
  T(CWv, R1 + 2359296, DD, DD, nullptr, DD);
  gemm_bt<EPI_TRANS><<<g4(1024, DD), blk, 0, stream>>>(Tb, R1 + 2359296, Cbv, CVt, nullptr,
      48, DD, DD, 0, 1.f, 0, 0, 512, 9, (size_t)DD * 512);
  gemm_bt<EPI_BF16S><<<g4(8192, 512), blk, 0, stream>>>(R6 /*CQ*/, CK, nullptr, Sc, nullptr,
      48, DD, DD, 512, scl, 12, (size_t)512 * DD, 0, 0, 0);
  softmax_bf16<512><<<8192, blk, 0, stream>>>(Sc);
  gemm8<EPI_BF16><<<g8(8192, DD), blk8, 0, stream>>>(Sc, CVt, nullptr, R4 + 1536, nullptr,
      8, 512, 512, 3072, 1.f, 12, (size_t)DD * 512, 0, 0, 0);

  // merged out = x + concat @ [Wo;CWo] + (bo+Cbo)
  T(Wo, R1, DD, DD, nullptr, 3072);
  T(CWo, R1 + 1536, DD, DD, nullptr, 3072);
  gemm8<EPI_ADD_X><<<g8(8192, DD), blk8, 0, stream>>>(R4, R1, biasm, out, x,
      48, 3072, 3072, DD, 1.f, 0, 0, 0, 0, 0);

  // FFN: LN -> W1+gelu (single N=6144) -> W2 (single K=6144) acc
  norm_ln<<<8192, blk, 0, stream>>>(x, lnw, lnb, R2);
  T(W1, R0, DD, FF, nullptr, DD);
  gemm8<EPI_GELU><<<g8(8192, FF), blk8, 0, stream>>>(R2, R0, b1, H, nullptr,
      24, DD, DD, FF, 1.f, 0, 0, 0, 0, 0);
  T(W2, R1, FF, DD, nullptr, FF);
  gemm8<EPI_ACC><<<g8(8192, DD), blk8, 0, stream>>>(H, R1, b2, out, nullptr,
      96, FF, FF, DD, 1.f, 0, 0, 0, 0, 0);
}

// Round 11
// 1170.323 us; speedup vs baseline: 1.7035x; 1.7035x over previous
//
#include <hip/hip_runtime.h>
#include <hip/hip_bf16.h>
#include <cmath>

#define DD 1536
#define FF 6144

typedef __bf16 bf16_t;
typedef __bf16 bf16x8 __attribute__((ext_vector_type(8)));
typedef __bf16 bf16x4 __attribute__((ext_vector_type(4)));
typedef float  f32x4  __attribute__((ext_vector_type(4)));

#define VM6 asm volatile("s_waitcnt vmcnt(6)" ::: "memory")
#define VM0 asm volatile("s_waitcnt vmcnt(0)" ::: "memory")
#define LGKM0 do { asm volatile("s_waitcnt lgkmcnt(0)" :::); __builtin_amdgcn_sched_barrier(0); } while (0)
#define BAR __builtin_amdgcn_s_barrier()

__device__ __forceinline__ void async_load16(const bf16_t* g, bf16_t* l) {
  __builtin_amdgcn_global_load_lds(
      (const __attribute__((address_space(1))) void*)g,
      (__attribute__((address_space(3))) void*)l, 16, 0, 0);
}

// inline-asm LDS read: NOT ordered vs global_load_lds by the compiler; ordering is
// done explicitly via {vmcnt; barrier} (RAW) and {lgkmcnt(0); sched_barrier} (use).
__device__ __forceinline__ bf16x8 ds_read128(unsigned int addr) {
  bf16x8 r;
  asm volatile("ds_read_b128 %0, %1" : "=v"(r) : "v"(addr));
  return r;
}

// bijective XCD-aware remap (m204)
__device__ __forceinline__ void xcd_remap(int& bx, int& by) {
  const int gx = gridDim.x, gy = gridDim.y;
  int wg = by * gx + bx;
  const int nwg = gx * gy;
  const int q = nwg >> 3, r = nwg & 7, xcd = wg & 7, o = wg >> 3;
  wg = (xcd < r ? xcd * (q + 1) : r * (q + 1) + (xcd - r) * q) + o;
  bx = wg % gx;
  by = wg / gx;
}

// ---------------- weight fp32 -> bf16 transpose; optional per-K scale; output row stride ldt
__global__ __launch_bounds__(256) void transpose_to_bf16(
    const float* __restrict__ W, bf16_t* __restrict__ Wt, int K, int N,
    const float* __restrict__ s, int ldt) {
  __shared__ float tile[32][33];
  const int tx = threadIdx.x, ty = threadIdx.y;  // 32 x 8
  const int n0 = blockIdx.x * 32, k0 = blockIdx.y * 32;
#pragma unroll
  for (int i = 0; i < 4; i++)
    tile[ty + 8 * i][tx] = W[(size_t)(k0 + ty + 8 * i) * N + n0 + tx];
  __syncthreads();
  const float sc = (s != nullptr) ? s[k0 + tx] : 1.f;
#pragma unroll
  for (int i = 0; i < 4; i++)
    Wt[(size_t)(n0 + ty + 8 * i) * ldt + k0 + tx] = (bf16_t)(tile[tx][ty + 8 * i] * sc);
}

// ---------------- biasm = a + b ----------------
__global__ __launch_bounds__(256) void bias_add2(
    const float* __restrict__ a, const float* __restrict__ b, float* __restrict__ o, int n) {
  const int i = blockIdx.x * 256 + threadIdx.x;
  if (i < n) o[i] = a[i] + b[i];
}

// ---------------- reduction helpers ----------------
__device__ __forceinline__ void breduce1(float& a) {
#pragma unroll
  for (int off = 32; off; off >>= 1) a += __shfl_xor(a, off);
  __shared__ float sa[4];
  const int w = threadIdx.x >> 6, ln = threadIdx.x & 63;
  if (ln == 0) sa[w] = a;
  __syncthreads();
  a = (sa[0] + sa[1]) + (sa[2] + sa[3]);
  __syncthreads();
}

__device__ __forceinline__ void breduce2(float& a, float& b) {
#pragma unroll
  for (int off = 32; off; off >>= 1) {
    a += __shfl_xor(a, off);
    b += __shfl_xor(b, off);
  }
  __shared__ float sa[4], sb[4];
  const int w = threadIdx.x >> 6, ln = threadIdx.x & 63;
  if (ln == 0) { sa[w] = a; sb[w] = b; }
  __syncthreads();
  a = (sa[0] + sa[1]) + (sa[2] + sa[3]);
  b = (sb[0] + sb[1]) + (sb[2] + sb[3]);
  __syncthreads();
}

// ---------------- x: xr = x*rq (bf16) + rqinv[row] = sqrt(ms+eps) ----------------
__global__ __launch_bounds__(256) void norm_x1(
    const float* __restrict__ x, bf16_t* __restrict__ xr, float* __restrict__ rqinv) {
  const int row = blockIdx.x, t = threadIdx.x;
  const float* p = x + (size_t)row * DD;
  f32x4 v0 = ((const f32x4*)p)[t];
  f32x4 v1 = 0.0f;
  if (t < 128) v1 = ((const f32x4*)p)[256 + t];
  float s2 = 0.f;
#pragma unroll
  for (int e = 0; e < 4; e++) s2 += v0[e] * v0[e];
  if (t < 128) {
#pragma unroll
    for (int e = 0; e < 4; e++) s2 += v1[e] * v1[e];
  }
  breduce1(s2);
  const float ms = s2 * (1.f / DD) + 1e-7f;
  const float rq = rsqrtf(ms);
  if (t == 0) rqinv[row] = sqrtf(ms);
  auto emit = [&](int ci, f32x4 v) {
    bf16x4 orr;
#pragma unroll
    for (int e = 0; e < 4; e++) orr[e] = (bf16_t)(v[e] * rq);
    *(bf16x4*)(xr + (size_t)row * DD + ci * 4) = orr;
  };
  emit(t, v0);
  if (t < 128) emit(256 + t, v1);
}

// ---------------- LayerNorm -> bf16 ----------------
__global__ __launch_bounds__(256) void norm_ln(
    const float* __restrict__ x, const float* __restrict__ w,
    const float* __restrict__ bb, bf16_t* __restrict__ o) {
  const int row = blockIdx.x, t = threadIdx.x;
  const float* p = x + (size_t)row * DD;
  f32x4 v0 = ((const f32x4*)p)[t];
  f32x4 v1 = 0.0f;
  if (t < 128) v1 = ((const f32x4*)p)[256 + t];
  float s = 0.f, s2 = 0.f;
#pragma unroll
  for (int e = 0; e < 4; e++) { s += v0[e]; s2 += v0[e] * v0[e]; }
  if (t < 128) {
#pragma unroll
    for (int e = 0; e < 4; e++) { s += v1[e]; s2 += v1[e] * v1[e]; }
  }
  breduce2(s, s2);
  const float mu = s * (1.f / DD);
  const float rln = rsqrtf(s2 * (1.f / DD) - mu * mu + 1e-5f);
  auto emit = [&](int ci, f32x4 v) {
    const int i0 = ci * 4;
    bf16x4 ov;
#pragma unroll
    for (int e = 0; e < 4; e++)
      ov[e] = (bf16_t)((v[e] - mu) * rln * w[i0 + e] + bb[i0 + e]);
    *(bf16x4*)(o + (size_t)row * DD + i0) = ov;
  };
  emit(t, v0);
  if (t < 128) emit(256 + t, v1);
}

// ---------------- text: Tb = raw bf16, Tck = text*rtq ----------
__global__ __launch_bounds__(256) void norm_t2(
    const float* __restrict__ te, bf16_t* __restrict__ tb, bf16_t* __restrict__ tck) {
  const int row = blockIdx.x, t = threadIdx.x;
  const float* p = te + (size_t)row * DD;
  f32x4 v0 = ((const f32x4*)p)[t];
  f32x4 v1 = 0.0f;
  if (t < 128) v1 = ((const f32x4*)p)[256 + t];
  float s2 = 0.f;
#pragma unroll
  for (int e = 0; e < 4; e++) s2 += v0[e] * v0[e];
  if (t < 128) {
#pragma unroll
    for (int e = 0; e < 4; e++) s2 += v1[e] * v1[e];
  }
  breduce1(s2);
  const float rq = rsqrtf(s2 * (1.f / DD) + 1e-7f);
  auto emit = [&](int ci, f32x4 v) {
    bf16x4 ob, oc;
#pragma unroll
    for (int e = 0; e < 4; e++) {
      ob[e] = (bf16_t)v[e];
      oc[e] = (bf16_t)(v[e] * rq);
    }
    const size_t o = (size_t)row * DD + ci * 4;
    *(bf16x4*)(tb + o) = ob;
    *(bf16x4*)(tck + o) = oc;
  };
  emit(t, v0);
  if (t < 128) emit(256 + t, v1);
}

// ---------------- in-place bf16 row softmax ----------------
template <int NC>
__global__ __launch_bounds__(256) void softmax_bf16(bf16_t* __restrict__ S) {
  const int t = threadIdx.x;
  bf16_t* sr = S + (size_t)blockIdx.x * NC;
  constexpr int NV = (NC / 8 + 255) / 256;
  float v[NV][8];
  float mx = -3.4e38f;
#pragma unroll
  for (int i = 0; i < NV; i++) {
    const int idx = t + i * 256;
    if (idx * 8 < NC) {
      bf16x8 b = ((const bf16x8*)sr)[idx];
#pragma unroll
      for (int e = 0; e < 8; e++) {
        v[i][e] = (float)b[e];
        mx = fmaxf(mx, v[i][e]);
      }
    }
  }
#pragma unroll
  for (int off = 32; off; off >>= 1) mx = fmaxf(mx, __shfl_xor(mx, off));
  __shared__ float sm[4];
  const int w = t >> 6, ln = t & 63;
  if (ln == 0) sm[w] = mx;
  __syncthreads();
  mx = fmaxf(fmaxf(sm[0], sm[1]), fmaxf(sm[2], sm[3]));
  __syncthreads();
  float sum = 0.f;
#pragma unroll
  for (int i = 0; i < NV; i++) {
    const int idx = t + i * 256;
    if (idx * 8 < NC) {
#pragma unroll
      for (int e = 0; e < 8; e++) {
        v[i][e] = __expf(v[i][e] - mx);
        sum += v[i][e];
      }
    }
  }
#pragma unroll
  for (int off = 32; off; off >>= 1) sum += __shfl_xor(sum, off);
  __shared__ float ss[4];
  if (ln == 0) ss[w] = sum;
  __syncthreads();
  sum = (ss[0] + ss[1]) + (ss[2] + ss[3]);
  const float inv = 1.f / sum;
#pragma unroll
  for (int i = 0; i < NV; i++) {
    const int idx = t + i * 256;
    if (idx * 8 < NC) {
      bf16x8 o;
#pragma unroll
      for (int e = 0; e < 8; e++) o[e] = (bf16_t)(v[i][e] * inv);
      ((bf16x8*)sr)[idx] = o;
    }
  }
}

enum { EPI_BF16 = 0, EPI_F32_SCALE = 1, EPI_ADD_X = 2, EPI_ACC = 3, EPI_GELU = 4, EPI_TRANS = 5, EPI_BF16S = 6, EPI_PROJ3 = 7 };

template <int EPI>
__device__ __forceinline__ void epi_frag(
    f32x4 v, int r0, int c, const float* bias, void* Cout, const float* Xres,
    int ldc, float scale, int t_ld, int t_bshift, size_t t_bstride) {
  const float bv = (bias != nullptr) ? bias[c] : 0.f;
  if constexpr (EPI == EPI_BF16) {
    bf16_t* C = (bf16_t*)Cout;
#pragma unroll
    for (int r = 0; r < 4; r++) C[(size_t)(r0 + r) * ldc + c] = (bf16_t)(v[r] + bv);
  } else if constexpr (EPI == EPI_F32_SCALE) {
    float* C = (float*)Cout;
#pragma unroll
    for (int r = 0; r < 4; r++) C[(size_t)(r0 + r) * ldc + c] = v[r] * scale;
  } else if constexpr (EPI == EPI_BF16S) {
    bf16_t* C = (bf16_t*)Cout;
#pragma unroll
    for (int r = 0; r < 4; r++) C[(size_t)(r0 + r) * ldc + c] = (bf16_t)(v[r] * scale);
  } else if constexpr (EPI == EPI_ADD_X) {
    float* C = (float*)Cout;
#pragma unroll
    for (int r = 0; r < 4; r++) {
      const size_t ix = (size_t)(r0 + r) * ldc + c;
      C[ix] = Xres[ix] + v[r] + bv;
    }
  } else if constexpr (EPI == EPI_ACC) {
    float* C = (float*)Cout;
#pragma unroll
    for (int r = 0; r < 4; r++) {
      const size_t ix = (size_t)(r0 + r) * ldc + c;
      C[ix] += v[r] + bv;
    }
  } else if constexpr (EPI == EPI_GELU) {
    bf16_t* C = (bf16_t*)Cout;
#pragma unroll
    for (int r = 0; r < 4; r++) {
      const float h = v[r] + bv;
      C[(size_t)(r0 + r) * ldc + c] = (bf16_t)(0.5f * h * (1.f + erff(h * 0.70710678118654752f)));
    }
  } else if constexpr (EPI == EPI_TRANS) {  // batched C^T: out[b][c][n]
    const int b = r0 >> t_bshift;
    const int n = r0 & ((1 << t_bshift) - 1);
    bf16_t* C = (bf16_t*)Cout + (size_t)b * t_bstride + (size_t)c * t_ld + n;
    bf16x4 o;
#pragma unroll
    for (int r = 0; r < 4; r++) o[r] = (bf16_t)(v[r] + bv);
    *(bf16x4*)C = o;
  } else {  // EPI_PROJ3: mega-projection. Cout=R4 (QK base, ldc 3072); arena-contiguous
            // Vt = Cout+25165824 (V^T batched, ld 4096), CQ = Cout+37748736 (ldc 1536).
            // Xres = rqinv[row] (per-row inverse rms factor, applied to V region only).
    bf16_t* base = (bf16_t*)Cout;
    if (c < 1536) {          // V^T with per-row descale
      const int b = r0 >> 12, n = r0 & 4095;
      bf16_t* C = base + 25165824 + (size_t)b * ((size_t)DD * 4096) + (size_t)c * 4096 + n;
      bf16x4 o;
#pragma unroll
      for (int r = 0; r < 4; r++) o[r] = (bf16_t)(v[r] * Xres[r0 + r] + bv);
      *(bf16x4*)C = o;
    } else if (c < 4608) {   // Q|K row-major, ldc 3072
#pragma unroll
      for (int r = 0; r < 4; r++) base[(size_t)(r0 + r) * 3072 + (c - 1536)] = (bf16_t)(v[r] + bv);
    } else {                 // CQ row-major, ldc 1536
      bf16_t* C = base + 37748736;
#pragma unroll
      for (int r = 0; r < 4; r++) C[(size_t)(r0 + r) * 1536 + (c - 4608)] = (bf16_t)(v[r] + bv);
    }
  }
}

// ---------------- gemm_bt: 128x128 tile, 4 waves, BK=32 (proven r2 kernel + batch-B) ------
template <int EPI>
__global__ __launch_bounds__(256) void gemm_bt(
    const bf16_t* __restrict__ A, const bf16_t* __restrict__ B,
    const float* __restrict__ bias, void* __restrict__ Cout,
    const float* __restrict__ Xres,
    int nK, int lda, int ldb, int ldc, float scale,
    int bsh, size_t bstr, int t_ld, int t_bshift, size_t t_bstride) {
  __shared__ __align__(16) bf16_t As[2][128 * 32];
  __shared__ __align__(16) bf16_t Bs[2][128 * 32];
  const int tid = threadIdx.x;
  int bx = blockIdx.x, by = blockIdx.y;
  xcd_remap(bx, by);
  const int m0 = by * 128, n0 = bx * 128;
  const int wave = tid >> 6, lane = tid & 63, l15 = lane & 15, hi = lane >> 4;
  const int wm = wave >> 1, wn = wave & 1;
  const int srow = tid >> 2, scol = (tid & 3) << 3;

  const bf16_t* Bb = bsh ? (B + (size_t)(m0 >> bsh) * bstr) : B;
  const bf16_t* ga = A + (size_t)(m0 + srow) * lda + scol;
  const bf16_t* gb = Bb + (size_t)(n0 + srow) * ldb + scol;
  const int lo = wave * 512;

  f32x4 acc[4][4];
#pragma unroll
  for (int i = 0; i < 4; i++)
#pragma unroll
    for (int j = 0; j < 4; j++) acc[i][j] = 0.0f;

  auto stage = [&](int buf, int kt) {
    const bf16_t* a = ga + (size_t)kt * 32;
    const bf16_t* b = gb + (size_t)kt * 32;
    async_load16(a, &As[buf][lo]);
    async_load16(a + (size_t)64 * lda, &As[buf][2048 + lo]);
    async_load16(b, &Bs[buf][lo]);
    async_load16(b + (size_t)64 * ldb, &Bs[buf][2048 + lo]);
  };

  auto compute = [&](int buf) {
    bf16x8 af[4], bg[4];
#pragma unroll
    for (int i = 0; i < 4; i++)
      af[i] = *(const bf16x8*)&As[buf][(wm * 64 + i * 16 + l15) * 32 + hi * 8];
#pragma unroll
    for (int j = 0; j < 4; j++)
      bg[j] = *(const bf16x8*)&Bs[buf][(wn * 64 + j * 16 + l15) * 32 + hi * 8];
#pragma unroll
    for (int i = 0; i < 4; i++)
#pragma unroll
      for (int j = 0; j < 4; j++)
        acc[i][j] = __builtin_amdgcn_mfma_f32_16x16x32_bf16(af[i], bg[j], acc[i][j], 0, 0, 0);
  };

  stage(0, 0);
  __syncthreads();
  for (int kt = 0; kt < nK; ++kt) {
    if (kt + 1 < nK) stage((kt + 1) & 1, kt + 1);
    compute(kt & 1);
    __syncthreads();
  }

#pragma unroll
  for (int i = 0; i < 4; i++) {
    const int r0 = m0 + wm * 64 + i * 16 + hi * 4;
#pragma unroll
    for (int j = 0; j < 4; j++) {
      const int c = n0 + wn * 64 + j * 16 + l15;
      epi_frag<EPI>(acc[i][j], r0, c, bias, Cout, Xres, ldc, scale, t_ld, t_bshift, t_bstride);
    }
  }
}

// ---------------- gemm8: 256x256, 8 waves, BK=64, 8-phase, asm ds_read (r9 verbatim) ------
// RAW: tile k confirmed at q3(k-1)'s {VM6; BAR}. ds_reads are inline asm; consumption
// fenced by {BAR; lgkmcnt(0); sched_barrier(0)} before each MFMA cluster (rule #18).
// WAR: B[buf] reads retire by q1's LGKM0+MM+BAR -> stgB(k+2)@q2 safe; A[buf] by q2's ->
// stgA(k+2)@q3 safe; As[buf^1] write @q0 is 2 barriers past its last reader.
template <int EPI>
__global__ __launch_bounds__(512, 2) void gemm8(
    const bf16_t* __restrict__ A, const bf16_t* __restrict__ B,
    const float* __restrict__ bias, void* __restrict__ Cout,
    const float* __restrict__ Xres,
    int nT, int lda, int ldb, int ldc, float scale,
    int bsh, size_t bstr, int t_ld, int t_bshift, size_t t_bstride) {
  __shared__ __align__(16) bf16_t As[2][256 * 64];
  __shared__ __align__(16) bf16_t Bs[2][256 * 64];
  const int tid = threadIdx.x;
  int bx = blockIdx.x, by = blockIdx.y;
  xcd_remap(bx, by);
  const int m0 = by * 256, n0 = bx * 256;
  const int wave = tid >> 6, lane = tid & 63, l15 = lane & 15, hi = lane >> 4;
  const int wm = wave >> 2, wn = wave & 3;  // 2 x 4 waves; per-wave 128x64 output

  const int srow = tid >> 3;
  const int scol = ((tid & 7) ^ (srow & 7)) << 3;
  const bf16_t* Bb = bsh ? (B + (size_t)(m0 >> bsh) * bstr) : B;
  const bf16_t* gA = A + (size_t)(m0 + srow) * lda + scol;
  const bf16_t* gB = Bb + (size_t)(n0 + srow) * ldb + scol;
  const int ldst = wave * 512;

  f32x4 acc[8][4];
#pragma unroll
  for (int i = 0; i < 8; i++)
#pragma unroll
    for (int j = 0; j < 4; j++) acc[i][j] = 0.0f;

  auto stgA = [&](int t, int half) {
    if (t >= nT) return;
    const int buf = t & 1, r0 = half << 7;
    const size_t kof = (size_t)t * 64;
    async_load16(gA + (size_t)r0 * lda + kof, &As[buf][r0 * 64 + ldst]);
    async_load16(gA + (size_t)(r0 + 64) * lda + kof, &As[buf][(r0 + 64) * 64 + ldst]);
  };
  auto stgB = [&](int t, int half) {
    if (t >= nT) return;
    const int buf = t & 1, r0 = half << 7;
    const size_t kof = (size_t)t * 64;
    async_load16(gB + (size_t)r0 * ldb + kof, &Bs[buf][r0 * 64 + ldst]);
    async_load16(gB + (size_t)(r0 + 64) * ldb + kof, &Bs[buf][(r0 + 64) * 64 + ldst]);
  };

  bf16x8 af[4][2], bg[2][2][2];
  auto LDA = [&](int buf, int mh) {
#pragma unroll
    for (int i = 0; i < 4; i++) {
      const int r = wm * 128 + (mh * 4 + i) * 16 + l15;
      const int rx = r & 7;
#pragma unroll
      for (int ks = 0; ks < 2; ks++)
        af[i][ks] = ds_read128((unsigned int)(size_t)&As[buf][r * 64 + (((hi + 4 * ks) ^ rx) << 3)]);
    }
  };
  auto LDB = [&](int buf, int nh) {
#pragma unroll
    for (int j = 0; j < 2; j++) {
      const int r = wn * 64 + (nh * 2 + j) * 16 + l15;
      const int rx = r & 7;
#pragma unroll
      for (int ks = 0; ks < 2; ks++)
        bg[nh][j][ks] = ds_read128((unsigned int)(size_t)&Bs[buf][r * 64 + (((hi + 4 * ks) ^ rx) << 3)]);
    }
  };
  auto MM = [&](int mh, int nh) {
    __builtin_amdgcn_s_setprio(1);
#pragma unroll
    for (int i = 0; i < 4; i++)
#pragma unroll
      for (int j = 0; j < 2; j++)
#pragma unroll
        for (int ks = 0; ks < 2; ks++)
          acc[mh * 4 + i][nh * 2 + j] = __builtin_amdgcn_mfma_f32_16x16x32_bf16(
              af[i][ks], bg[nh][j][ks], acc[mh * 4 + i][nh * 2 + j], 0, 0, 0);
    __builtin_amdgcn_s_setprio(0);
  };

  // prologue: tile0 fully + tile1 {Bl,Bh,Al}; confirm tile 0 (6 newer loads in flight)
  stgB(0, 0); stgB(0, 1); stgA(0, 0); stgA(0, 1);
  stgB(1, 0); stgB(1, 1); stgA(1, 0);
  if (nT > 1) { VM6; } else { VM0; }
  BAR;

  for (int k = 0; k < nT; ++k) {
    const int buf = k & 1;
    // q0: stage Ah(k+1); reads (tile k, confirmed last iter) pre-barrier
    stgA(k + 1, 1);
    LDA(buf, 0);
    LDB(buf, 0);
    BAR;
    LGKM0;
    MM(0, 0);
    BAR;
    // q1: read bg(nh1); B[buf] fully consumed after this phase
    LDB(buf, 1);
    BAR;
    LGKM0;
    MM(0, 1);
    BAR;
    // q2: stage Bl(k+2); read af(mh1); A[buf] fully consumed after this phase
    stgB(k + 2, 0);
    LDA(buf, 1);
    BAR;
    LGKM0;
    MM(1, 0);
    BAR;
    // q3: stage Bh,Al(k+2); confirm tile k+1 (counted; VM0 on tail)
    stgB(k + 2, 1);
    stgA(k + 2, 0);
    if (k + 2 < nT) { VM6; } else { VM0; }
    BAR;
    MM(1, 1);
    BAR;
  }

#pragma unroll
  for (int fi = 0; fi < 8; fi++) {
    const int r0 = m0 + wm * 128 + fi * 16 + hi * 4;
#pragma unroll
    for (int fj = 0; fj < 4; fj++) {
      const int c = n0 + wn * 64 + fj * 16 + l15;
      epi_frag<EPI>(acc[fi][fj], r0, c, bias, Cout, Xres, ldc, scale, t_ld, t_bshift, t_bstride);
    }
  }
}

// ---------------- host ----------------
extern "C" void kernel_launch(void* const* d_in, const int* in_sizes, int n_in,
                              void* d_out, int out_size, void* d_ws, size_t ws_size,
                              hipStream_t stream) {
  (void)in_sizes; (void)n_in; (void)out_size; (void)ws_size;
  const float* x   = (const float*)d_in[0];
  const float* te  = (const float*)d_in[1];
  const float* sqw = (const float*)d_in[2];
  const float* skw = (const float*)d_in[3];
  const float* cqw = (const float*)d_in[4];
  const float* ckw = (const float*)d_in[5];
  const float* lnw = (const float*)d_in[6];
  const float* lnb = (const float*)d_in[7];
  const float* Wq = (const float*)d_in[8];  const float* bq = (const float*)d_in[9];
  const float* Wk = (const float*)d_in[10]; const float* bk = (const float*)d_in[11];
  const float* Wv = (const float*)d_in[12]; const float* bv = (const float*)d_in[13];
  const float* Wo = (const float*)d_in[14]; const float* bo = (const float*)d_in[15];
  const float* CWq = (const float*)d_in[16]; const float* Cbq = (const float*)d_in[17];
  const float* CWk = (const float*)d_in[18]; const float* Cbk = (const float*)d_in[19];
  const float* CWv = (const float*)d_in[20]; const float* Cbv = (const float*)d_in[21];
  const float* CWo = (const float*)d_in[22]; const float* Cbo = (const float*)d_in[23];
  const float* W1 = (const float*)d_in[24]; const float* b1 = (const float*)d_in[25];
  const float* W2 = (const float*)d_in[26]; const float* b2 = (const float*)d_in[27];
  float* out = (float*)d_out;

  // ---- arena (bf16 el offsets); peak ~170 MB ----
  bf16_t* ws = (bf16_t*)d_ws;
  bf16_t* R0 = ws;                  // 9437184: [Wv|Wq|Wk|CWq]^T -> {CK,CVt,Sc} -> W1^T
  bf16_t* R1 = ws + 9437184;        // 9437184: CWk/CWv^T -> [Wo|CWo]^T -> W2^T
  bf16_t* R2 = ws + 18874368;       // 12582912: xr -> LNo
  bf16_t* Tb  = ws + 31457280;      // 1572864
  bf16_t* Tck = ws + 33030144;      // 1572864
  bf16_t* R4 = ws + 34603008;       // 25165824: Q|K(ldc3072) -> concat APre|CPre -> H[0:..]
  bf16_t* R5 = ws + 59768832;       // 12582912: V^T -> H mid   (= R4 + 25165824)
  bf16_t* R6 = ws + 72351744;       // 12582912: CQ -> H end    (= R4 + 37748736)
  bf16_t* S  = ws;                  // 33554432 overlay (self-attn scores)
  float* bcat4 = (float*)(ws + 84934656);    // 6144 f32 = [bv|bq|bk|Cbq]
  float* biasm = (float*)(ws + 84946944);    // 1536 f32 = bo+Cbo
  float* rqinv = (float*)(ws + 84950016);    // 8192 f32
  bf16_t* CK  = R0;
  bf16_t* CVt = R0 + 1572864;
  bf16_t* Sc  = R0 + 3145728;       // 8192x512 bf16
  bf16_t* H   = R4;                 // 8192x6144 (R4+R5+R6 contiguous)

  const dim3 blk(256), blk8(512), tb(32, 8);
  const float scl = 0.025515518153991442f;  // 1/sqrt(1536)

  auto T = [&](const float* W, bf16_t* Wt, int K, int N, const float* s, int ldt) {
    transpose_to_bf16<<<dim3(N / 32, K / 32), tb, 0, stream>>>(W, Wt, K, N, s, ldt);
  };
  auto g8 = [](int M, int N) { return dim3(N / 256, M / 256); };
  auto g4 = [](int M, int N) { return dim3(N / 128, M / 128); };

  // biases
  hipMemcpyAsync(bcat4,        bv,  DD * sizeof(float), hipMemcpyDeviceToDevice, stream);
  hipMemcpyAsync(bcat4 + DD,   bq,  DD * sizeof(float), hipMemcpyDeviceToDevice, stream);
  hipMemcpyAsync(bcat4 + 2*DD, bk,  DD * sizeof(float), hipMemcpyDeviceToDevice, stream);
  hipMemcpyAsync(bcat4 + 3*DD, Cbq, DD * sizeof(float), hipMemcpyDeviceToDevice, stream);
  bias_add2<<<6, blk, 0, stream>>>(bo, Cbo, biasm, DD);

  // norm: xr + per-row descale
  norm_x1<<<8192, blk, 0, stream>>>(x, R2, rqinv);

  // mega-projection: [V^T | Q|K | CQ] = xr @ [Wv | Wq*sqw | Wk*skw | CWq*cqw]^T, N=6144
  // (768 blocks = 3 exactly-full rounds; V region de-scaled per row via rqinv)
  T(Wv,  R0,               DD, DD, nullptr, DD);
  T(Wq,  R0 + 2359296,     DD, DD, sqw,     DD);
  T(Wk,  R0 + 4718592,     DD, DD, skw,     DD);
  T(CWq, R0 + 7077888,     DD, DD, cqw,     DD);
  gemm8<EPI_PROJ3><<<g8(8192, FF), blk8, 0, stream>>>(R2, R0, bcat4, R4, rqinv,
      24, DD, DD, 3072, 1.f, 0, 0, 0, 0, 0);

  // self-attention (batched over 2 via m0>>12)
  gemm8<EPI_BF16S><<<g8(8192, 4096), blk8, 0, stream>>>(R4 /*Q*/, R4 + DD /*K*/, nullptr, S, nullptr,
      24, 3072, 3072, 4096, scl, 12, (size_t)4096 * 3072, 0, 0, 0);
  softmax_bf16<4096><<<8192, blk, 0, stream>>>(S);
  gemm8<EPI_BF16><<<g8(8192, DD), blk8, 0, stream>>>(S, R5, nullptr, R4, nullptr,
      64, 4096, 4096, 3072, 1.f, 12, (size_t)DD * 4096, 0, 0, 0);

  // cross-attention
  norm_t2<<<1024, blk, 0, stream>>>(te, Tb, Tck);
  T(CWk, R1, DD, DD, ckw, DD);
  gemm_bt<EPI_BF16><<<g4(1024, DD), blk, 0, stream>>>(Tck, R1, Cbk, CK, nullptr,
      48, DD, DD, DD, 1.f, 0, 0, 0, 0, 0);
  T(CWv, R1 + 2359296, DD, DD, nullptr, DD);
  gemm_bt<EPI_TRANS><<<g4(1024, DD), blk, 0, stream>>>(Tb, R1 + 2359296, Cbv, CVt, nullptr,
      48, DD, DD, 0, 1.f, 0, 0, 512, 9, (size_t)DD * 512);
  gemm_bt<EPI_BF16S><<<g4(8192, 512), blk, 0, stream>>>(R6 /*CQ*/, CK, nullptr, Sc, nullptr,
      48, DD, DD, 512, scl, 12, (size_t)512 * DD, 0, 0, 0);
  softmax_bf16<512><<<8192, blk, 0, stream>>>(Sc);
  gemm8<EPI_BF16><<<g8(8192, DD), blk8, 0, stream>>>(Sc, CVt, nullptr, R4 + 1536, nullptr,
      8, 512, 512, 3072, 1.f, 12, (size_t)DD * 512, 0, 0, 0);

  // merged out = x + concat @ [Wo;CWo] + (bo+Cbo)
  T(Wo, R1, DD, DD, nullptr, 3072);
  T(CWo, R1 + 1536, DD, DD, nullptr, 3072);
  gemm8<EPI_ADD_X><<<g8(8192, DD), blk8, 0, stream>>>(R4, R1, biasm, out, x,
      48, 3072, 3072, DD, 1.f, 0, 0, 0, 0, 0);

  // FFN: LN -> W1+gelu (single N=6144) -> W2 (single K=6144) acc
  norm_ln<<<8192, blk, 0, stream>>>(x, lnw, lnb, R2);
  T(W1, R0, DD, FF, nullptr, DD);
  gemm8<EPI_GELU><<<g8(8192, FF), blk8, 0, stream>>>(R2, R0, b1, H, nullptr,
      24, DD, DD, FF, 1.f, 0, 0, 0, 0, 0);
  T(W2, R1, FF, DD, nullptr, FF);
  gemm8<EPI_ACC><<<g8(8192, DD), blk8, 0, stream>>>(H, R1, b2, out, nullptr,
      96, FF, FF, DD, 1.f, 0, 0, 0, 0, 0);
}

// Round 12
// 1148.660 us; speedup vs baseline: 1.7356x; 1.0189x over previous
//
#include <hip/hip_runtime.h>
#include <hip/hip_bf16.h>
#include <cmath>

#define DD 1536
#define FF 6144

typedef __bf16 bf16_t;
typedef __bf16 bf16x8 __attribute__((ext_vector_type(8)));
typedef __bf16 bf16x4 __attribute__((ext_vector_type(4)));
typedef float  f32x4  __attribute__((ext_vector_type(4)));

#define VM6 asm volatile("s_waitcnt vmcnt(6)" ::: "memory")
#define VM0 asm volatile("s_waitcnt vmcnt(0)" ::: "memory")
#define LGKM0 do { asm volatile("s_waitcnt lgkmcnt(0)" :::); __builtin_amdgcn_sched_barrier(0); } while (0)
#define BAR __builtin_amdgcn_s_barrier()

__device__ __forceinline__ void async_load16(const bf16_t* g, bf16_t* l) {
  __builtin_amdgcn_global_load_lds(
      (const __attribute__((address_space(1))) void*)g,
      (__attribute__((address_space(3))) void*)l, 16, 0, 0);
}

// inline-asm LDS read: NOT ordered vs global_load_lds by the compiler; ordering is
// done explicitly via {vmcnt; barrier} (RAW) and {lgkmcnt(0); sched_barrier} (use).
__device__ __forceinline__ bf16x8 ds_read128(unsigned int addr) {
  bf16x8 r;
  asm volatile("ds_read_b128 %0, %1" : "=v"(r) : "v"(addr));
  return r;
}

// bijective XCD-aware remap (m204)
__device__ __forceinline__ void xcd_remap(int& bx, int& by) {
  const int gx = gridDim.x, gy = gridDim.y;
  int wg = by * gx + bx;
  const int nwg = gx * gy;
  const int q = nwg >> 3, r = nwg & 7, xcd = wg & 7, o = wg >> 3;
  wg = (xcd < r ? xcd * (q + 1) : r * (q + 1) + (xcd - r) * q) + o;
  bx = wg % gx;
  by = wg / gx;
}

// ---------------- weight fp32 -> bf16 transpose; optional per-K scale; output row stride ldt
__global__ __launch_bounds__(256) void transpose_to_bf16(
    const float* __restrict__ W, bf16_t* __restrict__ Wt, int K, int N,
    const float* __restrict__ s, int ldt) {
  __shared__ float tile[32][33];
  const int tx = threadIdx.x, ty = threadIdx.y;  // 32 x 8
  const int n0 = blockIdx.x * 32, k0 = blockIdx.y * 32;
#pragma unroll
  for (int i = 0; i < 4; i++)
    tile[ty + 8 * i][tx] = W[(size_t)(k0 + ty + 8 * i) * N + n0 + tx];
  __syncthreads();
  const float sc = (s != nullptr) ? s[k0 + tx] : 1.f;
#pragma unroll
  for (int i = 0; i < 4; i++)
    Wt[(size_t)(n0 + ty + 8 * i) * ldt + k0 + tx] = (bf16_t)(tile[tx][ty + 8 * i] * sc);
}

// ---------------- biasm = a + b ----------------
__global__ __launch_bounds__(256) void bias_add2(
    const float* __restrict__ a, const float* __restrict__ b, float* __restrict__ o, int n) {
  const int i = blockIdx.x * 256 + threadIdx.x;
  if (i < n) o[i] = a[i] + b[i];
}

// ---------------- reduction helpers ----------------
__device__ __forceinline__ void breduce1(float& a) {
#pragma unroll
  for (int off = 32; off; off >>= 1) a += __shfl_xor(a, off);
  __shared__ float sa[4];
  const int w = threadIdx.x >> 6, ln = threadIdx.x & 63;
  if (ln == 0) sa[w] = a;
  __syncthreads();
  a = (sa[0] + sa[1]) + (sa[2] + sa[3]);
  __syncthreads();
}

__device__ __forceinline__ void breduce2(float& a, float& b) {
#pragma unroll
  for (int off = 32; off; off >>= 1) {
    a += __shfl_xor(a, off);
    b += __shfl_xor(b, off);
  }
  __shared__ float sa[4], sb[4];
  const int w = threadIdx.x >> 6, ln = threadIdx.x & 63;
  if (ln == 0) { sa[w] = a; sb[w] = b; }
  __syncthreads();
  a = (sa[0] + sa[1]) + (sa[2] + sa[3]);
  b = (sb[0] + sb[1]) + (sb[2] + sb[3]);
  __syncthreads();
}

// ---------------- x: xr = x*rq (bf16) + rqinv[row] = sqrt(ms+eps) ----------------
__global__ __launch_bounds__(256) void norm_x1(
    const float* __restrict__ x, bf16_t* __restrict__ xr, float* __restrict__ rqinv) {
  const int row = blockIdx.x, t = threadIdx.x;
  const float* p = x + (size_t)row * DD;
  f32x4 v0 = ((const f32x4*)p)[t];
  f32x4 v1 = 0.0f;
  if (t < 128) v1 = ((const f32x4*)p)[256 + t];
  float s2 = 0.f;
#pragma unroll
  for (int e = 0; e < 4; e++) s2 += v0[e] * v0[e];
  if (t < 128) {
#pragma unroll
    for (int e = 0; e < 4; e++) s2 += v1[e] * v1[e];
  }
  breduce1(s2);
  const float ms = s2 * (1.f / DD) + 1e-7f;
  const float rq = rsqrtf(ms);
  if (t == 0) rqinv[row] = sqrtf(ms);
  auto emit = [&](int ci, f32x4 v) {
    bf16x4 orr;
#pragma unroll
    for (int e = 0; e < 4; e++) orr[e] = (bf16_t)(v[e] * rq);
    *(bf16x4*)(xr + (size_t)row * DD + ci * 4) = orr;
  };
  emit(t, v0);
  if (t < 128) emit(256 + t, v1);
}

// ---------------- LayerNorm -> bf16 ----------------
__global__ __launch_bounds__(256) void norm_ln(
    const float* __restrict__ x, const float* __restrict__ w,
    const float* __restrict__ bb, bf16_t* __restrict__ o) {
  const int row = blockIdx.x, t = threadIdx.x;
  const float* p = x + (size_t)row * DD;
  f32x4 v0 = ((const f32x4*)p)[t];
  f32x4 v1 = 0.0f;
  if (t < 128) v1 = ((const f32x4*)p)[256 + t];
  float s = 0.f, s2 = 0.f;
#pragma unroll
  for (int e = 0; e < 4; e++) { s += v0[e]; s2 += v0[e] * v0[e]; }
  if (t < 128) {
#pragma unroll
    for (int e = 0; e < 4; e++) { s += v1[e]; s2 += v1[e] * v1[e]; }
  }
  breduce2(s, s2);
  const float mu = s * (1.f / DD);
  const float rln = rsqrtf(s2 * (1.f / DD) - mu * mu + 1e-5f);
  auto emit = [&](int ci, f32x4 v) {
    const int i0 = ci * 4;
    bf16x4 ov;
#pragma unroll
    for (int e = 0; e < 4; e++)
      ov[e] = (bf16_t)((v[e] - mu) * rln * w[i0 + e] + bb[i0 + e]);
    *(bf16x4*)(o + (size_t)row * DD + i0) = ov;
  };
  emit(t, v0);
  if (t < 128) emit(256 + t, v1);
}

// ---------------- text: Tb = raw bf16, Tck = text*rtq ----------
__global__ __launch_bounds__(256) void norm_t2(
    const float* __restrict__ te, bf16_t* __restrict__ tb, bf16_t* __restrict__ tck) {
  const int row = blockIdx.x, t = threadIdx.x;
  const float* p = te + (size_t)row * DD;
  f32x4 v0 = ((const f32x4*)p)[t];
  f32x4 v1 = 0.0f;
  if (t < 128) v1 = ((const f32x4*)p)[256 + t];
  float s2 = 0.f;
#pragma unroll
  for (int e = 0; e < 4; e++) s2 += v0[e] * v0[e];
  if (t < 128) {
#pragma unroll
    for (int e = 0; e < 4; e++) s2 += v1[e] * v1[e];
  }
  breduce1(s2);
  const float rq = rsqrtf(s2 * (1.f / DD) + 1e-7f);
  auto emit = [&](int ci, f32x4 v) {
    bf16x4 ob, oc;
#pragma unroll
    for (int e = 0; e < 4; e++) {
      ob[e] = (bf16_t)v[e];
      oc[e] = (bf16_t)(v[e] * rq);
    }
    const size_t o = (size_t)row * DD + ci * 4;
    *(bf16x4*)(tb + o) = ob;
    *(bf16x4*)(tck + o) = oc;
  };
  emit(t, v0);
  if (t < 128) emit(256 + t, v1);
}

// ---------------- in-place bf16 row softmax ----------------
template <int NC>
__global__ __launch_bounds__(256) void softmax_bf16(bf16_t* __restrict__ S) {
  const int t = threadIdx.x;
  bf16_t* sr = S + (size_t)blockIdx.x * NC;
  constexpr int NV = (NC / 8 + 255) / 256;
  float v[NV][8];
  float mx = -3.4e38f;
#pragma unroll
  for (int i = 0; i < NV; i++) {
    const int idx = t + i * 256;
    if (idx * 8 < NC) {
      bf16x8 b = ((const bf16x8*)sr)[idx];
#pragma unroll
      for (int e = 0; e < 8; e++) {
        v[i][e] = (float)b[e];
        mx = fmaxf(mx, v[i][e]);
      }
    }
  }
#pragma unroll
  for (int off = 32; off; off >>= 1) mx = fmaxf(mx, __shfl_xor(mx, off));
  __shared__ float sm[4];
  const int w = t >> 6, ln = t & 63;
  if (ln == 0) sm[w] = mx;
  __syncthreads();
  mx = fmaxf(fmaxf(sm[0], sm[1]), fmaxf(sm[2], sm[3]));
  __syncthreads();
  float sum = 0.f;
#pragma unroll
  for (int i = 0; i < NV; i++) {
    const int idx = t + i * 256;
    if (idx * 8 < NC) {
#pragma unroll
      for (int e = 0; e < 8; e++) {
        v[i][e] = __expf(v[i][e] - mx);
        sum += v[i][e];
      }
    }
  }
#pragma unroll
  for (int off = 32; off; off >>= 1) sum += __shfl_xor(sum, off);
  __shared__ float ss[4];
  if (ln == 0) ss[w] = sum;
  __syncthreads();
  sum = (ss[0] + ss[1]) + (ss[2] + ss[3]);
  const float inv = 1.f / sum;
#pragma unroll
  for (int i = 0; i < NV; i++) {
    const int idx = t + i * 256;
    if (idx * 8 < NC) {
      bf16x8 o;
#pragma unroll
      for (int e = 0; e < 8; e++) o[e] = (bf16_t)(v[i][e] * inv);
      ((bf16x8*)sr)[idx] = o;
    }
  }
}

enum { EPI_BF16 = 0, EPI_F32_SCALE = 1, EPI_ADD_X = 2, EPI_ACC = 3, EPI_GELU = 4, EPI_TRANS = 5, EPI_BF16S = 6, EPI_PROJ3 = 7 };

template <int EPI>
__device__ __forceinline__ void epi_frag(
    f32x4 v, int r0, int c, const float* bias, void* Cout, const float* Xres,
    int ldc, float scale, int t_ld, int t_bshift, size_t t_bstride) {
  const float bv = (bias != nullptr) ? bias[c] : 0.f;
  if constexpr (EPI == EPI_BF16) {
    bf16_t* C = (bf16_t*)Cout;
#pragma unroll
    for (int r = 0; r < 4; r++) C[(size_t)(r0 + r) * ldc + c] = (bf16_t)(v[r] + bv);
  } else if constexpr (EPI == EPI_F32_SCALE) {
    float* C = (float*)Cout;
#pragma unroll
    for (int r = 0; r < 4; r++) C[(size_t)(r0 + r) * ldc + c] = v[r] * scale;
  } else if constexpr (EPI == EPI_BF16S) {
    bf16_t* C = (bf16_t*)Cout;
#pragma unroll
    for (int r = 0; r < 4; r++) C[(size_t)(r0 + r) * ldc + c] = (bf16_t)(v[r] * scale);
  } else if constexpr (EPI == EPI_ADD_X) {
    float* C = (float*)Cout;
#pragma unroll
    for (int r = 0; r < 4; r++) {
      const size_t ix = (size_t)(r0 + r) * ldc + c;
      C[ix] = Xres[ix] + v[r] + bv;
    }
  } else if constexpr (EPI == EPI_ACC) {
    float* C = (float*)Cout;
#pragma unroll
    for (int r = 0; r < 4; r++) {
      const size_t ix = (size_t)(r0 + r) * ldc + c;
      C[ix] += v[r] + bv;
    }
  } else if constexpr (EPI == EPI_GELU) {
    bf16_t* C = (bf16_t*)Cout;
#pragma unroll
    for (int r = 0; r < 4; r++) {
      const float h = v[r] + bv;
      C[(size_t)(r0 + r) * ldc + c] = (bf16_t)(0.5f * h * (1.f + erff(h * 0.70710678118654752f)));
    }
  } else if constexpr (EPI == EPI_TRANS) {  // batched C^T: out[b][c][n]
    const int b = r0 >> t_bshift;
    const int n = r0 & ((1 << t_bshift) - 1);
    bf16_t* C = (bf16_t*)Cout + (size_t)b * t_bstride + (size_t)c * t_ld + n;
    bf16x4 o;
#pragma unroll
    for (int r = 0; r < 4; r++) o[r] = (bf16_t)(v[r] + bv);
    *(bf16x4*)C = o;
  } else {  // EPI_PROJ3: mega-projection. Cout=R4 (QK base, ldc 3072); arena-contiguous
            // Vt = Cout+25165824 (V^T batched, ld 4096), CQ = Cout+37748736 (ldc 1536).
            // Xres = rqinv[row] (per-row inverse rms factor, applied to V region only).
    bf16_t* base = (bf16_t*)Cout;
    if (c < 1536) {          // V^T with per-row descale
      const int b = r0 >> 12, n = r0 & 4095;
      bf16_t* C = base + 25165824 + (size_t)b * ((size_t)DD * 4096) + (size_t)c * 4096 + n;
      bf16x4 o;
#pragma unroll
      for (int r = 0; r < 4; r++) o[r] = (bf16_t)(v[r] * Xres[r0 + r] + bv);
      *(bf16x4*)C = o;
    } else if (c < 4608) {   // Q|K row-major, ldc 3072
#pragma unroll
      for (int r = 0; r < 4; r++) base[(size_t)(r0 + r) * 3072 + (c - 1536)] = (bf16_t)(v[r] + bv);
    } else {                 // CQ row-major, ldc 1536
      bf16_t* C = base + 37748736;
#pragma unroll
      for (int r = 0; r < 4; r++) C[(size_t)(r0 + r) * 1536 + (c - 4608)] = (bf16_t)(v[r] + bv);
    }
  }
}

// ---------------- gemm_bt: 128x128 tile, 4 waves, BK=32 (proven r2 kernel + batch-B) ------
template <int EPI>
__global__ __launch_bounds__(256) void gemm_bt(
    const bf16_t* __restrict__ A, const bf16_t* __restrict__ B,
    const float* __restrict__ bias, void* __restrict__ Cout,
    const float* __restrict__ Xres,
    int nK, int lda, int ldb, int ldc, float scale,
    int bsh, size_t bstr, int t_ld, int t_bshift, size_t t_bstride) {
  __shared__ __align__(16) bf16_t As[2][128 * 32];
  __shared__ __align__(16) bf16_t Bs[2][128 * 32];
  const int tid = threadIdx.x;
  int bx = blockIdx.x, by = blockIdx.y;
  xcd_remap(bx, by);
  const int m0 = by * 128, n0 = bx * 128;
  const int wave = tid >> 6, lane = tid & 63, l15 = lane & 15, hi = lane >> 4;
  const int wm = wave >> 1, wn = wave & 1;
  const int srow = tid >> 2, scol = (tid & 3) << 3;

  const bf16_t* Bb = bsh ? (B + (size_t)(m0 >> bsh) * bstr) : B;
  const bf16_t* ga = A + (size_t)(m0 + srow) * lda + scol;
  const bf16_t* gb = Bb + (size_t)(n0 + srow) * ldb + scol;
  const int lo = wave * 512;

  f32x4 acc[4][4];
#pragma unroll
  for (int i = 0; i < 4; i++)
#pragma unroll
    for (int j = 0; j < 4; j++) acc[i][j] = 0.0f;

  auto stage = [&](int buf, int kt) {
    const bf16_t* a = ga + (size_t)kt * 32;
    const bf16_t* b = gb + (size_t)kt * 32;
    async_load16(a, &As[buf][lo]);
    async_load16(a + (size_t)64 * lda, &As[buf][2048 + lo]);
    async_load16(b, &Bs[buf][lo]);
    async_load16(b + (size_t)64 * ldb, &Bs[buf][2048 + lo]);
  };

  auto compute = [&](int buf) {
    bf16x8 af[4], bg[4];
#pragma unroll
    for (int i = 0; i < 4; i++)
      af[i] = *(const bf16x8*)&As[buf][(wm * 64 + i * 16 + l15) * 32 + hi * 8];
#pragma unroll
    for (int j = 0; j < 4; j++)
      bg[j] = *(const bf16x8*)&Bs[buf][(wn * 64 + j * 16 + l15) * 32 + hi * 8];
#pragma unroll
    for (int i = 0; i < 4; i++)
#pragma unroll
      for (int j = 0; j < 4; j++)
        acc[i][j] = __builtin_amdgcn_mfma_f32_16x16x32_bf16(af[i], bg[j], acc[i][j], 0, 0, 0);
  };

  stage(0, 0);
  __syncthreads();
  for (int kt = 0; kt < nK; ++kt) {
    if (kt + 1 < nK) stage((kt + 1) & 1, kt + 1);
    compute(kt & 1);
    __syncthreads();
  }

#pragma unroll
  for (int i = 0; i < 4; i++) {
    const int r0 = m0 + wm * 64 + i * 16 + hi * 4;
#pragma unroll
    for (int j = 0; j < 4; j++) {
      const int c = n0 + wn * 64 + j * 16 + l15;
      epi_frag<EPI>(acc[i][j], r0, c, bias, Cout, Xres, ldc, scale, t_ld, t_bshift, t_bstride);
    }
  }
}

// ---------------- gemm8: 256x256, 8 waves, BK=64, 8-phase, asm ds_read ----------
// Schedule identical to r9/r11 (verified). NEW: constant-folded LDS addressing — the
// swizzle lane-term rx = row&7 = l15&7 is independent of i/mh/j/nh (row deltas are
// multiples of 8 rows), so every fragment address = one of 4 per-lane byte bases
// (A/B x ks0/ks1) + compile-time delta buf*32768 + (mh*4+i)*2048 (A) or
// buf*32768 + (nh*2+j)*2048 (B). k-loop unrolled x2 so buf is a literal (nT always
// even here) -> <=1 VALU per ds_read instead of full recompute.
template <int EPI>
__global__ __launch_bounds__(512, 2) void gemm8(
    const bf16_t* __restrict__ A, const bf16_t* __restrict__ B,
    const float* __restrict__ bias, void* __restrict__ Cout,
    const float* __restrict__ Xres,
    int nT, int lda, int ldb, int ldc, float scale,
    int bsh, size_t bstr, int t_ld, int t_bshift, size_t t_bstride) {
  __shared__ __align__(16) bf16_t As[2][256 * 64];
  __shared__ __align__(16) bf16_t Bs[2][256 * 64];
  const int tid = threadIdx.x;
  int bx = blockIdx.x, by = blockIdx.y;
  xcd_remap(bx, by);
  const int m0 = by * 256, n0 = bx * 256;
  const int wave = tid >> 6, lane = tid & 63, l15 = lane & 15, hi = lane >> 4;
  const int wm = wave >> 2, wn = wave & 3;  // 2 x 4 waves; per-wave 128x64 output

  const int srow = tid >> 3;
  const int scol = ((tid & 7) ^ (srow & 7)) << 3;
  const bf16_t* Bb = bsh ? (B + (size_t)(m0 >> bsh) * bstr) : B;
  const bf16_t* gA = A + (size_t)(m0 + srow) * lda + scol;
  const bf16_t* gB = Bb + (size_t)(n0 + srow) * ldb + scol;
  const int ldst = wave * 512;

  // per-lane ds_read byte bases (buf 0); buf1 = +32768
  const unsigned swz0 = (unsigned)(((hi ^ (l15 & 7)) << 3) * 2);
  const unsigned swz1 = (unsigned)((((hi + 4) ^ (l15 & 7)) << 3) * 2);
  const unsigned aBase = (unsigned)(size_t)&As[0][0] + (unsigned)((wm * 128 + l15) * 128);
  const unsigned bBase = (unsigned)(size_t)&Bs[0][0] + (unsigned)((wn * 64 + l15) * 128);
  const unsigned a0 = aBase + swz0, a1 = aBase + swz1;
  const unsigned b0 = bBase + swz0, b1 = bBase + swz1;

  f32x4 acc[8][4];
#pragma unroll
  for (int i = 0; i < 8; i++)
#pragma unroll
    for (int j = 0; j < 4; j++) acc[i][j] = 0.0f;

  auto stgA = [&](int t, int half) {
    if (t >= nT) return;
    const int buf = t & 1, r0 = half << 7;
    const size_t kof = (size_t)t * 64;
    async_load16(gA + (size_t)r0 * lda + kof, &As[buf][r0 * 64 + ldst]);
    async_load16(gA + (size_t)(r0 + 64) * lda + kof, &As[buf][(r0 + 64) * 64 + ldst]);
  };
  auto stgB = [&](int t, int half) {
    if (t >= nT) return;
    const int buf = t & 1, r0 = half << 7;
    const size_t kof = (size_t)t * 64;
    async_load16(gB + (size_t)r0 * ldb + kof, &Bs[buf][r0 * 64 + ldst]);
    async_load16(gB + (size_t)(r0 + 64) * ldb + kof, &Bs[buf][(r0 + 64) * 64 + ldst]);
  };

  bf16x8 af[4][2], bg[2][2][2];
  auto LDA = [&](int buf, int mh) {
#pragma unroll
    for (int i = 0; i < 4; i++) {
      const unsigned d = (unsigned)(buf * 32768 + (mh * 4 + i) * 2048);
      af[i][0] = ds_read128(a0 + d);
      af[i][1] = ds_read128(a1 + d);
    }
  };
  auto LDB = [&](int buf, int nh) {
#pragma unroll
    for (int j = 0; j < 2; j++) {
      const unsigned d = (unsigned)(buf * 32768 + (nh * 2 + j) * 2048);
      bg[nh][j][0] = ds_read128(b0 + d);
      bg[nh][j][1] = ds_read128(b1 + d);
    }
  };
  auto MM = [&](int mh, int nh) {
    __builtin_amdgcn_s_setprio(1);
#pragma unroll
    for (int i = 0; i < 4; i++)
#pragma unroll
      for (int j = 0; j < 2; j++)
#pragma unroll
        for (int ks = 0; ks < 2; ks++)
          acc[mh * 4 + i][nh * 2 + j] = __builtin_amdgcn_mfma_f32_16x16x32_bf16(
              af[i][ks], bg[nh][j][ks], acc[mh * 4 + i][nh * 2 + j], 0, 0, 0);
    __builtin_amdgcn_s_setprio(0);
  };

  // one K-tile iteration; buf is a compile-time literal at each call site
  auto iter = [&](int k, int buf) {
    // q0: stage Ah(k+1); reads (tile k, confirmed last iter) pre-barrier
    stgA(k + 1, 1);
    LDA(buf, 0);
    LDB(buf, 0);
    BAR;
    LGKM0;
    MM(0, 0);
    BAR;
    // q1: read bg(nh1); B[buf] fully consumed after this phase
    LDB(buf, 1);
    BAR;
    LGKM0;
    MM(0, 1);
    BAR;
    // q2: stage Bl(k+2); read af(mh1); A[buf] fully consumed after this phase
    stgB(k + 2, 0);
    LDA(buf, 1);
    BAR;
    LGKM0;
    MM(1, 0);
    BAR;
    // q3: stage Bh,Al(k+2); confirm tile k+1 (counted; VM0 on tail)
    stgB(k + 2, 1);
    stgA(k + 2, 0);
    if (k + 2 < nT) { VM6; } else { VM0; }
    BAR;
    MM(1, 1);
    BAR;
  };

  // prologue: tile0 fully + tile1 {Bl,Bh,Al}; confirm tile 0 (6 newer loads in flight)
  stgB(0, 0); stgB(0, 1); stgA(0, 0); stgA(0, 1);
  stgB(1, 0); stgB(1, 1); stgA(1, 0);
  if (nT > 1) { VM6; } else { VM0; }
  BAR;

  for (int k = 0; k < nT; k += 2) {  // nT is even for all call sites
    iter(k, 0);
    iter(k + 1, 1);
  }

#pragma unroll
  for (int fi = 0; fi < 8; fi++) {
    const int r0 = m0 + wm * 128 + fi * 16 + hi * 4;
#pragma unroll
    for (int fj = 0; fj < 4; fj++) {
      const int c = n0 + wn * 64 + fj * 16 + l15;
      epi_frag<EPI>(acc[fi][fj], r0, c, bias, Cout, Xres, ldc, scale, t_ld, t_bshift, t_bstride);
    }
  }
}

// ---------------- host ----------------
extern "C" void kernel_launch(void* const* d_in, const int* in_sizes, int n_in,
                              void* d_out, int out_size, void* d_ws, size_t ws_size,
                              hipStream_t stream) {
  (void)in_sizes; (void)n_in; (void)out_size; (void)ws_size;
  const float* x   = (const float*)d_in[0];
  const float* te  = (const float*)d_in[1];
  const float* sqw = (const float*)d_in[2];
  const float* skw = (const float*)d_in[3];
  const float* cqw = (const float*)d_in[4];
  const float* ckw = (const float*)d_in[5];
  const float* lnw = (const float*)d_in[6];
  const float* lnb = (const float*)d_in[7];
  const float* Wq = (const float*)d_in[8];  const float* bq = (const float*)d_in[9];
  const float* Wk = (const float*)d_in[10]; const float* bk = (const float*)d_in[11];
  const float* Wv = (const float*)d_in[12]; const float* bv = (const float*)d_in[13];
  const float* Wo = (const float*)d_in[14]; const float* bo = (const float*)d_in[15];
  const float* CWq = (const float*)d_in[16]; const float* Cbq = (const float*)d_in[17];
  const float* CWk = (const float*)d_in[18]; const float* Cbk = (const float*)d_in[19];
  const float* CWv = (const float*)d_in[20]; const float* Cbv = (const float*)d_in[21];
  const float* CWo = (const float*)d_in[22]; const float* Cbo = (const float*)d_in[23];
  const float* W1 = (const float*)d_in[24]; const float* b1 = (const float*)d_in[25];
  const float* W2 = (const float*)d_in[26]; const float* b2 = (const float*)d_in[27];
  float* out = (float*)d_out;

  // ---- arena (bf16 el offsets); peak ~170 MB ----
  bf16_t* ws = (bf16_t*)d_ws;
  bf16_t* R0 = ws;                  // 9437184: [Wv|Wq|Wk|CWq]^T -> {CK,CVt,Sc} -> W1^T
  bf16_t* R1 = ws + 9437184;        // 9437184: CWk/CWv^T -> [Wo|CWo]^T -> W2^T
  bf16_t* R2 = ws + 18874368;       // 12582912: xr -> LNo
  bf16_t* Tb  = ws + 31457280;      // 1572864
  bf16_t* Tck = ws + 33030144;      // 1572864
  bf16_t* R4 = ws + 34603008;       // 25165824: Q|K(ldc3072) -> concat APre|CPre -> H[0:..]
  bf16_t* R5 = ws + 59768832;       // 12582912: V^T -> H mid   (= R4 + 25165824)
  bf16_t* R6 = ws + 72351744;       // 12582912: CQ -> H end    (= R4 + 37748736)
  bf16_t* S  = ws;                  // 33554432 overlay (self-attn scores)
  float* bcat4 = (float*)(ws + 84934656);    // 6144 f32 = [bv|bq|bk|Cbq]
  float* biasm = (float*)(ws + 84946944);    // 1536 f32 = bo+Cbo
  float* rqinv = (float*)(ws + 84950016);    // 8192 f32
  bf16_t* CK  = R0;
  bf16_t* CVt = R0 + 1572864;
  bf16_t* Sc  = R0 + 3145728;       // 8192x512 bf16
  bf16_t* H   = R4;                 // 8192x6144 (R4+R5+R6 contiguous)

  const dim3 blk(256), blk8(512), tb(32, 8);
  const float scl = 0.025515518153991442f;  // 1/sqrt(1536)

  auto T = [&](const float* W, bf16_t* Wt, int K, int N, const float* s, int ldt) {
    transpose_to_bf16<<<dim3(N / 32, K / 32), tb, 0, stream>>>(W, Wt, K, N, s, ldt);
  };
  auto g8 = [](int M, int N) { return dim3(N / 256, M / 256); };
  auto g4 = [](int M, int N) { return dim3(N / 128, M / 128); };

  // biases
  hipMemcpyAsync(bcat4,        bv,  DD * sizeof(float), hipMemcpyDeviceToDevice, stream);
  hipMemcpyAsync(bcat4 + DD,   bq,  DD * sizeof(float), hipMemcpyDeviceToDevice, stream);
  hipMemcpyAsync(bcat4 + 2*DD, bk,  DD * sizeof(float), hipMemcpyDeviceToDevice, stream);
  hipMemcpyAsync(bcat4 + 3*DD, Cbq, DD * sizeof(float), hipMemcpyDeviceToDevice, stream);
  bias_add2<<<6, blk, 0, stream>>>(bo, Cbo, biasm, DD);

  // norm: xr + per-row descale
  norm_x1<<<8192, blk, 0, stream>>>(x, R2, rqinv);

  // mega-projection: [V^T | Q|K | CQ] = xr @ [Wv | Wq*sqw | Wk*skw | CWq*cqw]^T, N=6144
  T(Wv,  R0,               DD, DD, nullptr, DD);
  T(Wq,  R0 + 2359296,     DD, DD, sqw,     DD);
  T(Wk,  R0 + 4718592,     DD, DD, skw,     DD);
  T(CWq, R0 + 7077888,     DD, DD, cqw,     DD);
  gemm8<EPI_PROJ3><<<g8(8192, FF), blk8, 0, stream>>>(R2, R0, bcat4, R4, rqinv,
      24, DD, DD, 3072, 1.f, 0, 0, 0, 0, 0);

  // self-attention (batched over 2 via m0>>12)
  gemm8<EPI_BF16S><<<g8(8192, 4096), blk8, 0, stream>>>(R4 /*Q*/, R4 + DD /*K*/, nullptr, S, nullptr,
      24, 3072, 3072, 4096, scl, 12, (size_t)4096 * 3072, 0, 0, 0);
  softmax_bf16<4096><<<8192, blk, 0, stream>>>(S);
  gemm8<EPI_BF16><<<g8(8192, DD), blk8, 0, stream>>>(S, R5, nullptr, R4, nullptr,
      64, 4096, 4096, 3072, 1.f, 12, (size_t)DD * 4096, 0, 0, 0);

  // cross-attention
  norm_t2<<<1024, blk, 0, stream>>>(te, Tb, Tck);
  T(CWk, R1, DD, DD, ckw, DD);
  gemm_bt<EPI_BF16><<<g4(1024, DD), blk, 0, stream>>>(Tck, R1, Cbk, CK, nullptr,
      48, DD, DD, DD, 1.f, 0, 0, 0, 0, 0);
  T(CWv, R1 + 2359296, DD, DD, nullptr, DD);
  gemm_bt<EPI_TRANS><<<g4(1024, DD), blk, 0, stream>>>(Tb, R1 + 2359296, Cbv, CVt, nullptr,
      48, DD, DD, 0, 1.f, 0, 0, 512, 9, (size_t)DD * 512);
  gemm_bt<EPI_BF16S><<<g4(8192, 512), blk, 0, stream>>>(R6 /*CQ*/, CK, nullptr, Sc, nullptr,
      48, DD, DD, 512, scl, 12, (size_t)512 * DD, 0, 0, 0);
  softmax_bf16<512><<<8192, blk, 0, stream>>>(Sc);
  gemm8<EPI_BF16><<<g8(8192, DD), blk8, 0, stream>>>(Sc, CVt, nullptr, R4 + 1536, nullptr,
      8, 512, 512, 3072, 1.f, 12, (size_t)DD * 512, 0, 0, 0);

  // merged out = x + concat @ [Wo;CWo] + (bo+Cbo)
  T(Wo, R1, DD, DD, nullptr, 3072);
  T(CWo, R1 + 1536, DD, DD, nullptr, 3072);
  gemm8<EPI_ADD_X><<<g8(8192, DD), blk8, 0, stream>>>(R4, R1, biasm, out, x,
      48, 3072, 3072, DD, 1.f, 0, 0, 0, 0, 0);

  // FFN: LN -> W1+gelu (single N=6144) -> W2 (single K=6144) acc
  norm_ln<<<8192, blk, 0, stream>>>(x, lnw, lnb, R2);
  T(W1, R0, DD, FF, nullptr, DD);
  gemm8<EPI_GELU><<<g8(8192, FF), blk8, 0, stream>>>(R2, R0, b1, H, nullptr,
      24, DD, DD, FF, 1.f, 0, 0, 0, 0, 0);
  T(W2, R1, FF, DD, nullptr, FF);
  gemm8<EPI_ACC><<<g8(8192, DD), blk8, 0, stream>>>(H, R1, b2, out, nullptr,
      96, FF, FF, DD, 1.f, 0, 0, 0, 0, 0);
}

// Round 13
// 1125.606 us; speedup vs baseline: 1.7712x; 1.0205x over previous
//
#include <hip/hip_runtime.h>
#include <hip/hip_bf16.h>
#include <cmath>

#define DD 1536
#define FF 6144

typedef __bf16 bf16_t;
typedef __bf16 bf16x8 __attribute__((ext_vector_type(8)));
typedef __bf16 bf16x4 __attribute__((ext_vector_type(4)));
typedef float  f32x4  __attribute__((ext_vector_type(4)));

#define VM6 asm volatile("s_waitcnt vmcnt(6)" ::: "memory")
#define VM0 asm volatile("s_waitcnt vmcnt(0)" ::: "memory")
#define LGKM0 do { asm volatile("s_waitcnt lgkmcnt(0)" :::); __builtin_amdgcn_sched_barrier(0); } while (0)
#define BAR __builtin_amdgcn_s_barrier()

__device__ __forceinline__ void async_load16(const bf16_t* g, bf16_t* l) {
  __builtin_amdgcn_global_load_lds(
      (const __attribute__((address_space(1))) void*)g,
      (__attribute__((address_space(3))) void*)l, 16, 0, 0);
}

// inline-asm LDS read: NOT ordered vs global_load_lds by the compiler; ordering is
// done explicitly via {vmcnt; barrier} (RAW) and {lgkmcnt(0); sched_barrier} (use).
__device__ __forceinline__ bf16x8 ds_read128(unsigned int addr) {
  bf16x8 r;
  asm volatile("ds_read_b128 %0, %1" : "=v"(r) : "v"(addr));
  return r;
}

// bijective XCD-aware remap (m204)
__device__ __forceinline__ void xcd_remap(int& bx, int& by) {
  const int gx = gridDim.x, gy = gridDim.y;
  int wg = by * gx + bx;
  const int nwg = gx * gy;
  const int q = nwg >> 3, r = nwg & 7, xcd = wg & 7, o = wg >> 3;
  wg = (xcd < r ? xcd * (q + 1) : r * (q + 1) + (xcd - r) * q) + o;
  bx = wg % gx;
  by = wg / gx;
}

// ---------------- weight fp32 -> bf16 transpose; optional per-K scale; output row stride ldt
__global__ __launch_bounds__(256) void transpose_to_bf16(
    const float* __restrict__ W, bf16_t* __restrict__ Wt, int K, int N,
    const float* __restrict__ s, int ldt) {
  __shared__ float tile[32][33];
  const int tx = threadIdx.x, ty = threadIdx.y;  // 32 x 8
  const int n0 = blockIdx.x * 32, k0 = blockIdx.y * 32;
#pragma unroll
  for (int i = 0; i < 4; i++)
    tile[ty + 8 * i][tx] = W[(size_t)(k0 + ty + 8 * i) * N + n0 + tx];
  __syncthreads();
  const float sc = (s != nullptr) ? s[k0 + tx] : 1.f;
#pragma unroll
  for (int i = 0; i < 4; i++)
    Wt[(size_t)(n0 + ty + 8 * i) * ldt + k0 + tx] = (bf16_t)(tile[tx][ty + 8 * i] * sc);
}

// ---------------- biasm = a + b ----------------
__global__ __launch_bounds__(256) void bias_add2(
    const float* __restrict__ a, const float* __restrict__ b, float* __restrict__ o, int n) {
  const int i = blockIdx.x * 256 + threadIdx.x;
  if (i < n) o[i] = a[i] + b[i];
}

// ---------------- reduction helpers ----------------
__device__ __forceinline__ void breduce1(float& a) {
#pragma unroll
  for (int off = 32; off; off >>= 1) a += __shfl_xor(a, off);
  __shared__ float sa[4];
  const int w = threadIdx.x >> 6, ln = threadIdx.x & 63;
  if (ln == 0) sa[w] = a;
  __syncthreads();
  a = (sa[0] + sa[1]) + (sa[2] + sa[3]);
  __syncthreads();
}

__device__ __forceinline__ void breduce2(float& a, float& b) {
#pragma unroll
  for (int off = 32; off; off >>= 1) {
    a += __shfl_xor(a, off);
    b += __shfl_xor(b, off);
  }
  __shared__ float sa[4], sb[4];
  const int w = threadIdx.x >> 6, ln = threadIdx.x & 63;
  if (ln == 0) { sa[w] = a; sb[w] = b; }
  __syncthreads();
  a = (sa[0] + sa[1]) + (sa[2] + sa[3]);
  b = (sb[0] + sb[1]) + (sb[2] + sb[3]);
  __syncthreads();
}

// ---------------- x: xr = x*rq (bf16) + rqinv[row] = sqrt(ms+eps) ----------------
__global__ __launch_bounds__(256) void norm_x1(
    const float* __restrict__ x, bf16_t* __restrict__ xr, float* __restrict__ rqinv) {
  const int row = blockIdx.x, t = threadIdx.x;
  const float* p = x + (size_t)row * DD;
  f32x4 v0 = ((const f32x4*)p)[t];
  f32x4 v1 = 0.0f;
  if (t < 128) v1 = ((const f32x4*)p)[256 + t];
  float s2 = 0.f;
#pragma unroll
  for (int e = 0; e < 4; e++) s2 += v0[e] * v0[e];
  if (t < 128) {
#pragma unroll
    for (int e = 0; e < 4; e++) s2 += v1[e] * v1[e];
  }
  breduce1(s2);
  const float ms = s2 * (1.f / DD) + 1e-7f;
  const float rq = rsqrtf(ms);
  if (t == 0) rqinv[row] = sqrtf(ms);
  auto emit = [&](int ci, f32x4 v) {
    bf16x4 orr;
#pragma unroll
    for (int e = 0; e < 4; e++) orr[e] = (bf16_t)(v[e] * rq);
    *(bf16x4*)(xr + (size_t)row * DD + ci * 4) = orr;
  };
  emit(t, v0);
  if (t < 128) emit(256 + t, v1);
}

// ---------------- LayerNorm -> bf16 ----------------
__global__ __launch_bounds__(256) void norm_ln(
    const float* __restrict__ x, const float* __restrict__ w,
    const float* __restrict__ bb, bf16_t* __restrict__ o) {
  const int row = blockIdx.x, t = threadIdx.x;
  const float* p = x + (size_t)row * DD;
  f32x4 v0 = ((const f32x4*)p)[t];
  f32x4 v1 = 0.0f;
  if (t < 128) v1 = ((const f32x4*)p)[256 + t];
  float s = 0.f, s2 = 0.f;
#pragma unroll
  for (int e = 0; e < 4; e++) { s += v0[e]; s2 += v0[e] * v0[e]; }
  if (t < 128) {
#pragma unroll
    for (int e = 0; e < 4; e++) { s += v1[e]; s2 += v1[e] * v1[e]; }
  }
  breduce2(s, s2);
  const float mu = s * (1.f / DD);
  const float rln = rsqrtf(s2 * (1.f / DD) - mu * mu + 1e-5f);
  auto emit = [&](int ci, f32x4 v) {
    const int i0 = ci * 4;
    bf16x4 ov;
#pragma unroll
    for (int e = 0; e < 4; e++)
      ov[e] = (bf16_t)((v[e] - mu) * rln * w[i0 + e] + bb[i0 + e]);
    *(bf16x4*)(o + (size_t)row * DD + i0) = ov;
  };
  emit(t, v0);
  if (t < 128) emit(256 + t, v1);
}

// ---------------- text: Tb = raw bf16, Tck = text*rtq ----------
__global__ __launch_bounds__(256) void norm_t2(
    const float* __restrict__ te, bf16_t* __restrict__ tb, bf16_t* __restrict__ tck) {
  const int row = blockIdx.x, t = threadIdx.x;
  const float* p = te + (size_t)row * DD;
  f32x4 v0 = ((const f32x4*)p)[t];
  f32x4 v1 = 0.0f;
  if (t < 128) v1 = ((const f32x4*)p)[256 + t];
  float s2 = 0.f;
#pragma unroll
  for (int e = 0; e < 4; e++) s2 += v0[e] * v0[e];
  if (t < 128) {
#pragma unroll
    for (int e = 0; e < 4; e++) s2 += v1[e] * v1[e];
  }
  breduce1(s2);
  const float rq = rsqrtf(s2 * (1.f / DD) + 1e-7f);
  auto emit = [&](int ci, f32x4 v) {
    bf16x4 ob, oc;
#pragma unroll
    for (int e = 0; e < 4; e++) {
      ob[e] = (bf16_t)v[e];
      oc[e] = (bf16_t)(v[e] * rq);
    }
    const size_t o = (size_t)row * DD + ci * 4;
    *(bf16x4*)(tb + o) = ob;
    *(bf16x4*)(tck + o) = oc;
  };
  emit(t, v0);
  if (t < 128) emit(256 + t, v1);
}

// ---------------- in-place bf16 row softmax ----------------
template <int NC>
__global__ __launch_bounds__(256) void softmax_bf16(bf16_t* __restrict__ S) {
  const int t = threadIdx.x;
  bf16_t* sr = S + (size_t)blockIdx.x * NC;
  constexpr int NV = (NC / 8 + 255) / 256;
  float v[NV][8];
  float mx = -3.4e38f;
#pragma unroll
  for (int i = 0; i < NV; i++) {
    const int idx = t + i * 256;
    if (idx * 8 < NC) {
      bf16x8 b = ((const bf16x8*)sr)[idx];
#pragma unroll
      for (int e = 0; e < 8; e++) {
        v[i][e] = (float)b[e];
        mx = fmaxf(mx, v[i][e]);
      }
    }
  }
#pragma unroll
  for (int off = 32; off; off >>= 1) mx = fmaxf(mx, __shfl_xor(mx, off));
  __shared__ float sm[4];
  const int w = t >> 6, ln = t & 63;
  if (ln == 0) sm[w] = mx;
  __syncthreads();
  mx = fmaxf(fmaxf(sm[0], sm[1]), fmaxf(sm[2], sm[3]));
  __syncthreads();
  float sum = 0.f;
#pragma unroll
  for (int i = 0; i < NV; i++) {
    const int idx = t + i * 256;
    if (idx * 8 < NC) {
#pragma unroll
      for (int e = 0; e < 8; e++) {
        v[i][e] = __expf(v[i][e] - mx);
        sum += v[i][e];
      }
    }
  }
#pragma unroll
  for (int off = 32; off; off >>= 1) sum += __shfl_xor(sum, off);
  __shared__ float ss[4];
  if (ln == 0) ss[w] = sum;
  __syncthreads();
  sum = (ss[0] + ss[1]) + (ss[2] + ss[3]);
  const float inv = 1.f / sum;
#pragma unroll
  for (int i = 0; i < NV; i++) {
    const int idx = t + i * 256;
    if (idx * 8 < NC) {
      bf16x8 o;
#pragma unroll
      for (int e = 0; e < 8; e++) o[e] = (bf16_t)(v[i][e] * inv);
      ((bf16x8*)sr)[idx] = o;
    }
  }
}

enum { EPI_BF16 = 0, EPI_F32_SCALE = 1, EPI_ADD_X = 2, EPI_ACC = 3, EPI_GELU = 4, EPI_TRANS = 5, EPI_BF16S = 6, EPI_PROJ3 = 7 };

template <int EPI>
__device__ __forceinline__ void epi_frag(
    f32x4 v, int r0, int c, const float* bias, void* Cout, const float* Xres,
    int ldc, float scale, int t_ld, int t_bshift, size_t t_bstride) {
  const float bv = (bias != nullptr) ? bias[c] : 0.f;
  if constexpr (EPI == EPI_BF16) {
    bf16_t* C = (bf16_t*)Cout;
#pragma unroll
    for (int r = 0; r < 4; r++) C[(size_t)(r0 + r) * ldc + c] = (bf16_t)(v[r] + bv);
  } else if constexpr (EPI == EPI_F32_SCALE) {
    float* C = (float*)Cout;
#pragma unroll
    for (int r = 0; r < 4; r++) C[(size_t)(r0 + r) * ldc + c] = v[r] * scale;
  } else if constexpr (EPI == EPI_BF16S) {
    bf16_t* C = (bf16_t*)Cout;
#pragma unroll
    for (int r = 0; r < 4; r++) C[(size_t)(r0 + r) * ldc + c] = (bf16_t)(v[r] * scale);
  } else if constexpr (EPI == EPI_ADD_X) {
    float* C = (float*)Cout;
#pragma unroll
    for (int r = 0; r < 4; r++) {
      const size_t ix = (size_t)(r0 + r) * ldc + c;
      C[ix] = Xres[ix] + v[r] + bv;
    }
  } else if constexpr (EPI == EPI_ACC) {
    float* C = (float*)Cout;
#pragma unroll
    for (int r = 0; r < 4; r++) {
      const size_t ix = (size_t)(r0 + r) * ldc + c;
      C[ix] += v[r] + bv;
    }
  } else if constexpr (EPI == EPI_GELU) {
    bf16_t* C = (bf16_t*)Cout;
#pragma unroll
    for (int r = 0; r < 4; r++) {
      const float h = v[r] + bv;
      C[(size_t)(r0 + r) * ldc + c] = (bf16_t)(0.5f * h * (1.f + erff(h * 0.70710678118654752f)));
    }
  } else if constexpr (EPI == EPI_TRANS) {  // batched C^T: out[b][c][n]
    const int b = r0 >> t_bshift;
    const int n = r0 & ((1 << t_bshift) - 1);
    bf16_t* C = (bf16_t*)Cout + (size_t)b * t_bstride + (size_t)c * t_ld + n;
    bf16x4 o;
#pragma unroll
    for (int r = 0; r < 4; r++) o[r] = (bf16_t)(v[r] + bv);
    *(bf16x4*)C = o;
  } else {  // EPI_PROJ3: mega-projection. Cout=R4 (QK base, ldc 3072); arena-contiguous
            // Vt = Cout+25165824 (V^T batched, ld 4096), CQ = Cout+37748736 (ldc 1536).
            // Xres = rqinv[row] (per-row inverse rms factor, applied to V region only).
    bf16_t* base = (bf16_t*)Cout;
    if (c < 1536) {          // V^T with per-row descale
      const int b = r0 >> 12, n = r0 & 4095;
      bf16_t* C = base + 25165824 + (size_t)b * ((size_t)DD * 4096) + (size_t)c * 4096 + n;
      bf16x4 o;
#pragma unroll
      for (int r = 0; r < 4; r++) o[r] = (bf16_t)(v[r] * Xres[r0 + r] + bv);
      *(bf16x4*)C = o;
    } else if (c < 4608) {   // Q|K row-major, ldc 3072
#pragma unroll
      for (int r = 0; r < 4; r++) base[(size_t)(r0 + r) * 3072 + (c - 1536)] = (bf16_t)(v[r] + bv);
    } else {                 // CQ row-major, ldc 1536
      bf16_t* C = base + 37748736;
#pragma unroll
      for (int r = 0; r < 4; r++) C[(size_t)(r0 + r) * 1536 + (c - 4608)] = (bf16_t)(v[r] + bv);
    }
  }
}

// ---------------- gemm_bt: 128x128 tile, 4 waves, BK=32 (proven r2 kernel + batch-B) ------
template <int EPI>
__global__ __launch_bounds__(256) void gemm_bt(
    const bf16_t* __restrict__ A, const bf16_t* __restrict__ B,
    const float* __restrict__ bias, void* __restrict__ Cout,
    const float* __restrict__ Xres,
    int nK, int lda, int ldb, int ldc, float scale,
    int bsh, size_t bstr, int t_ld, int t_bshift, size_t t_bstride) {
  __shared__ __align__(16) bf16_t As[2][128 * 32];
  __shared__ __align__(16) bf16_t Bs[2][128 * 32];
  const int tid = threadIdx.x;
  int bx = blockIdx.x, by = blockIdx.y;
  xcd_remap(bx, by);
  const int m0 = by * 128, n0 = bx * 128;
  const int wave = tid >> 6, lane = tid & 63, l15 = lane & 15, hi = lane >> 4;
  const int wm = wave >> 1, wn = wave & 1;
  const int srow = tid >> 2, scol = (tid & 3) << 3;

  const bf16_t* Bb = bsh ? (B + (size_t)(m0 >> bsh) * bstr) : B;
  const bf16_t* ga = A + (size_t)(m0 + srow) * lda + scol;
  const bf16_t* gb = Bb + (size_t)(n0 + srow) * ldb + scol;
  const int lo = wave * 512;

  f32x4 acc[4][4];
#pragma unroll
  for (int i = 0; i < 4; i++)
#pragma unroll
    for (int j = 0; j < 4; j++) acc[i][j] = 0.0f;

  auto stage = [&](int buf, int kt) {
    const bf16_t* a = ga + (size_t)kt * 32;
    const bf16_t* b = gb + (size_t)kt * 32;
    async_load16(a, &As[buf][lo]);
    async_load16(a + (size_t)64 * lda, &As[buf][2048 + lo]);
    async_load16(b, &Bs[buf][lo]);
    async_load16(b + (size_t)64 * ldb, &Bs[buf][2048 + lo]);
  };

  auto compute = [&](int buf) {
    bf16x8 af[4], bg[4];
#pragma unroll
    for (int i = 0; i < 4; i++)
      af[i] = *(const bf16x8*)&As[buf][(wm * 64 + i * 16 + l15) * 32 + hi * 8];
#pragma unroll
    for (int j = 0; j < 4; j++)
      bg[j] = *(const bf16x8*)&Bs[buf][(wn * 64 + j * 16 + l15) * 32 + hi * 8];
#pragma unroll
    for (int i = 0; i < 4; i++)
#pragma unroll
      for (int j = 0; j < 4; j++)
        acc[i][j] = __builtin_amdgcn_mfma_f32_16x16x32_bf16(af[i], bg[j], acc[i][j], 0, 0, 0);
  };

  stage(0, 0);
  __syncthreads();
  for (int kt = 0; kt < nK; ++kt) {
    if (kt + 1 < nK) stage((kt + 1) & 1, kt + 1);
    compute(kt & 1);
    __syncthreads();
  }

#pragma unroll
  for (int i = 0; i < 4; i++) {
    const int r0 = m0 + wm * 64 + i * 16 + hi * 4;
#pragma unroll
    for (int j = 0; j < 4; j++) {
      const int c = n0 + wn * 64 + j * 16 + l15;
      epi_frag<EPI>(acc[i][j], r0, c, bias, Cout, Xres, ldc, scale, t_ld, t_bshift, t_bstride);
    }
  }
}

// ---------------- gemm8: 256x256, 8 waves, BK=64, 3-barrier free-run schedule ----------
// NEW (r13): mid-phase barriers removed — waves free-run through {reads; lgkm0; MFMA}
// within regions so one wave's MFMAs overlap another's ds_reads (m114 co-scheduling).
// Remaining barriers, each justified:
//   q1-end: all Bs[buf] reads (LDB q0/q1, complete per-wave before MM) globalized
//           -> stgB(k+2,0) in region B is WAR-safe.
//   q2-end: all As[buf] reads (LDA(buf,1), complete before MM(1,0)) globalized
//           -> stgA(k+2,0)/stgB(k+2,1) in region C are WAR-safe.
//   q3-end: after per-wave VM6 (<=6 outstanding = {Bl,Bh,Al}(k+2) => Ah(k+1) and all
//           older drained => tile k+1 landed; VM0 on tails where skipped stages break
//           the count) -> globalizes the RAW confirm for k+1's reads (r6 lesson).
// stgA(k+1,1)@regionA writes As[nbuf]; its last readers finished by q2-end(k-1).
template <int EPI>
__global__ __launch_bounds__(512, 2) void gemm8(
    const bf16_t* __restrict__ A, const bf16_t* __restrict__ B,
    const float* __restrict__ bias, void* __restrict__ Cout,
    const float* __restrict__ Xres,
    int nT, int lda, int ldb, int ldc, float scale,
    int bsh, size_t bstr, int t_ld, int t_bshift, size_t t_bstride) {
  __shared__ __align__(16) bf16_t As[2][256 * 64];
  __shared__ __align__(16) bf16_t Bs[2][256 * 64];
  const int tid = threadIdx.x;
  int bx = blockIdx.x, by = blockIdx.y;
  xcd_remap(bx, by);
  const int m0 = by * 256, n0 = bx * 256;
  const int wave = tid >> 6, lane = tid & 63, l15 = lane & 15, hi = lane >> 4;
  const int wm = wave >> 2, wn = wave & 3;  // 2 x 4 waves; per-wave 128x64 output

  const int srow = tid >> 3;
  const int scol = ((tid & 7) ^ (srow & 7)) << 3;
  const bf16_t* Bb = bsh ? (B + (size_t)(m0 >> bsh) * bstr) : B;
  const bf16_t* gA = A + (size_t)(m0 + srow) * lda + scol;
  const bf16_t* gB = Bb + (size_t)(n0 + srow) * ldb + scol;
  const int ldst = wave * 512;

  // per-lane ds_read byte bases (buf 0); buf1 = +32768
  const unsigned swz0 = (unsigned)(((hi ^ (l15 & 7)) << 3) * 2);
  const unsigned swz1 = (unsigned)((((hi + 4) ^ (l15 & 7)) << 3) * 2);
  const unsigned aBase = (unsigned)(size_t)&As[0][0] + (unsigned)((wm * 128 + l15) * 128);
  const unsigned bBase = (unsigned)(size_t)&Bs[0][0] + (unsigned)((wn * 64 + l15) * 128);
  const unsigned a0 = aBase + swz0, a1 = aBase + swz1;
  const unsigned b0 = bBase + swz0, b1 = bBase + swz1;

  f32x4 acc[8][4];
#pragma unroll
  for (int i = 0; i < 8; i++)
#pragma unroll
    for (int j = 0; j < 4; j++) acc[i][j] = 0.0f;

  auto stgA = [&](int t, int half) {
    if (t >= nT) return;
    const int buf = t & 1, r0 = half << 7;
    const size_t kof = (size_t)t * 64;
    async_load16(gA + (size_t)r0 * lda + kof, &As[buf][r0 * 64 + ldst]);
    async_load16(gA + (size_t)(r0 + 64) * lda + kof, &As[buf][(r0 + 64) * 64 + ldst]);
  };
  auto stgB = [&](int t, int half) {
    if (t >= nT) return;
    const int buf = t & 1, r0 = half << 7;
    const size_t kof = (size_t)t * 64;
    async_load16(gB + (size_t)r0 * ldb + kof, &Bs[buf][r0 * 64 + ldst]);
    async_load16(gB + (size_t)(r0 + 64) * ldb + kof, &Bs[buf][(r0 + 64) * 64 + ldst]);
  };

  bf16x8 af[4][2], bg[2][2][2];
  auto LDA = [&](int buf, int mh) {
#pragma unroll
    for (int i = 0; i < 4; i++) {
      const unsigned d = (unsigned)(buf * 32768 + (mh * 4 + i) * 2048);
      af[i][0] = ds_read128(a0 + d);
      af[i][1] = ds_read128(a1 + d);
    }
  };
  auto LDB = [&](int buf, int nh) {
#pragma unroll
    for (int j = 0; j < 2; j++) {
      const unsigned d = (unsigned)(buf * 32768 + (nh * 2 + j) * 2048);
      bg[nh][j][0] = ds_read128(b0 + d);
      bg[nh][j][1] = ds_read128(b1 + d);
    }
  };
  auto MM = [&](int mh, int nh) {
    __builtin_amdgcn_s_setprio(1);
#pragma unroll
    for (int i = 0; i < 4; i++)
#pragma unroll
      for (int j = 0; j < 2; j++)
#pragma unroll
        for (int ks = 0; ks < 2; ks++)
          acc[mh * 4 + i][nh * 2 + j] = __builtin_amdgcn_mfma_f32_16x16x32_bf16(
              af[i][ks], bg[nh][j][ks], acc[mh * 4 + i][nh * 2 + j], 0, 0, 0);
    __builtin_amdgcn_s_setprio(0);
  };

  // one K-tile iteration; buf is a compile-time literal at each call site
  auto iter = [&](int k, int buf) {
    // region A (q0+q1): free-run reads+MFMA, no internal barrier
    stgA(k + 1, 1);
    LDA(buf, 0);
    LDB(buf, 0);
    LGKM0;
    MM(0, 0);
    LDB(buf, 1);
    LGKM0;
    MM(0, 1);
    BAR;  // q1-end: B[buf] reads globally complete
    // region B (q2)
    stgB(k + 2, 0);
    LDA(buf, 1);
    LGKM0;
    MM(1, 0);
    BAR;  // q2-end: A[buf] reads globally complete
    // region C (q3)
    stgB(k + 2, 1);
    stgA(k + 2, 0);
    MM(1, 1);
    if (k + 2 < nT) { VM6; } else { VM0; }
    BAR;  // q3-end: tile k+1 confirmed globally
  };

  // prologue: tile0 fully + tile1 {Bl,Bh,Al}; confirm tile 0 (6 newer loads in flight)
  stgB(0, 0); stgB(0, 1); stgA(0, 0); stgA(0, 1);
  stgB(1, 0); stgB(1, 1); stgA(1, 0);
  if (nT > 1) { VM6; } else { VM0; }
  BAR;

  for (int k = 0; k < nT; k += 2) {  // nT is even for all call sites
    iter(k, 0);
    iter(k + 1, 1);
  }

#pragma unroll
  for (int fi = 0; fi < 8; fi++) {
    const int r0 = m0 + wm * 128 + fi * 16 + hi * 4;
#pragma unroll
    for (int fj = 0; fj < 4; fj++) {
      const int c = n0 + wn * 64 + fj * 16 + l15;
      epi_frag<EPI>(acc[fi][fj], r0, c, bias, Cout, Xres, ldc, scale, t_ld, t_bshift, t_bstride);
    }
  }
}

// ---------------- host ----------------
extern "C" void kernel_launch(void* const* d_in, const int* in_sizes, int n_in,
                              void* d_out, int out_size, void* d_ws, size_t ws_size,
                              hipStream_t stream) {
  (void)in_sizes; (void)n_in; (void)out_size; (void)ws_size;
  const float* x   = (const float*)d_in[0];
  const float* te  = (const float*)d_in[1];
  const float* sqw = (const float*)d_in[2];
  const float* skw = (const float*)d_in[3];
  const float* cqw = (const float*)d_in[4];
  const float* ckw = (const float*)d_in[5];
  const float* lnw = (const float*)d_in[6];
  const float* lnb = (const float*)d_in[7];
  const float* Wq = (const float*)d_in[8];  const float* bq = (const float*)d_in[9];
  const float* Wk = (const float*)d_in[10]; const float* bk = (const float*)d_in[11];
  const float* Wv = (const float*)d_in[12]; const float* bv = (const float*)d_in[13];
  const float* Wo = (const float*)d_in[14]; const float* bo = (const float*)d_in[15];
  const float* CWq = (const float*)d_in[16]; const float* Cbq = (const float*)d_in[17];
  const float* CWk = (const float*)d_in[18]; const float* Cbk = (const float*)d_in[19];
  const float* CWv = (const float*)d_in[20]; const float* Cbv = (const float*)d_in[21];
  const float* CWo = (const float*)d_in[22]; const float* Cbo = (const float*)d_in[23];
  const float* W1 = (const float*)d_in[24]; const float* b1 = (const float*)d_in[25];
  const float* W2 = (const float*)d_in[26]; const float* b2 = (const float*)d_in[27];
  float* out = (float*)d_out;

  // ---- arena (bf16 el offsets); peak ~170 MB ----
  bf16_t* ws = (bf16_t*)d_ws;
  bf16_t* R0 = ws;                  // 9437184: [Wv|Wq|Wk|CWq]^T -> {CK,CVt,Sc} -> W1^T
  bf16_t* R1 = ws + 9437184;        // 9437184: CWk/CWv^T -> [Wo|CWo]^T -> W2^T
  bf16_t* R2 = ws + 18874368;       // 12582912: xr -> LNo
  bf16_t* Tb  = ws + 31457280;      // 1572864
  bf16_t* Tck = ws + 33030144;      // 1572864
  bf16_t* R4 = ws + 34603008;       // 25165824: Q|K(ldc3072) -> concat APre|CPre -> H[0:..]
  bf16_t* R5 = ws + 59768832;       // 12582912: V^T -> H mid   (= R4 + 25165824)
  bf16_t* R6 = ws + 72351744;       // 12582912: CQ -> H end    (= R4 + 37748736)
  bf16_t* S  = ws;                  // 33554432 overlay (self-attn scores)
  float* bcat4 = (float*)(ws + 84934656);    // 6144 f32 = [bv|bq|bk|Cbq]
  float* biasm = (float*)(ws + 84946944);    // 1536 f32 = bo+Cbo
  float* rqinv = (float*)(ws + 84950016);    // 8192 f32
  bf16_t* CK  = R0;
  bf16_t* CVt = R0 + 1572864;
  bf16_t* Sc  = R0 + 3145728;       // 8192x512 bf16
  bf16_t* H   = R4;                 // 8192x6144 (R4+R5+R6 contiguous)

  const dim3 blk(256), blk8(512), tb(32, 8);
  const float scl = 0.025515518153991442f;  // 1/sqrt(1536)

  auto T = [&](const float* W, bf16_t* Wt, int K, int N, const float* s, int ldt) {
    transpose_to_bf16<<<dim3(N / 32, K / 32), tb, 0, stream>>>(W, Wt, K, N, s, ldt);
  };
  auto g8 = [](int M, int N) { return dim3(N / 256, M / 256); };
  auto g4 = [](int M, int N) { return dim3(N / 128, M / 128); };

  // biases
  hipMemcpyAsync(bcat4,        bv,  DD * sizeof(float), hipMemcpyDeviceToDevice, stream);
  hipMemcpyAsync(bcat4 + DD,   bq,  DD * sizeof(float), hipMemcpyDeviceToDevice, stream);
  hipMemcpyAsync(bcat4 + 2*DD, bk,  DD * sizeof(float), hipMemcpyDeviceToDevice, stream);
  hipMemcpyAsync(bcat4 + 3*DD, Cbq, DD * sizeof(float), hipMemcpyDeviceToDevice, stream);
  bias_add2<<<6, blk, 0, stream>>>(bo, Cbo, biasm, DD);

  // norm: xr + per-row descale
  norm_x1<<<8192, blk, 0, stream>>>(x, R2, rqinv);

  // mega-projection: [V^T | Q|K | CQ] = xr @ [Wv | Wq*sqw | Wk*skw | CWq*cqw]^T, N=6144
  T(Wv,  R0,               DD, DD, nullptr, DD);
  T(Wq,  R0 + 2359296,     DD, DD, sqw,     DD);
  T(Wk,  R0 + 4718592,     DD, DD, skw,     DD);
  T(CWq, R0 + 7077888,     DD, DD, cqw,     DD);
  gemm8<EPI_PROJ3><<<g8(8192, FF), blk8, 0, stream>>>(R2, R0, bcat4, R4, rqinv,
      24, DD, DD, 3072, 1.f, 0, 0, 0, 0, 0);

  // self-attention (batched over 2 via m0>>12)
  gemm8<EPI_BF16S><<<g8(8192, 4096), blk8, 0, stream>>>(R4 /*Q*/, R4 + DD /*K*/, nullptr, S, nullptr,
      24, 3072, 3072, 4096, scl, 12, (size_t)4096 * 3072, 0, 0, 0);
  softmax_bf16<4096><<<8192, blk, 0, stream>>>(S);
  gemm8<EPI_BF16><<<g8(8192, DD), blk8, 0, stream>>>(S, R5, nullptr, R4, nullptr,
      64, 4096, 4096, 3072, 1.f, 12, (size_t)DD * 4096, 0, 0, 0);

  // cross-attention
  norm_t2<<<1024, blk, 0, stream>>>(te, Tb, Tck);
  T(CWk, R1, DD, DD, ckw, DD);
  gemm_bt<EPI_BF16><<<g4(1024, DD), blk, 0, stream>>>(Tck, R1, Cbk, CK, nullptr,
      48, DD, DD, DD, 1.f, 0, 0, 0, 0, 0);
  T(CWv, R1 + 2359296, DD, DD, nullptr, DD);
  gemm_bt<EPI_TRANS><<<g4(1024, DD), blk, 0, stream>>>(Tb, R1 + 2359296, Cbv, CVt, nullptr,
      48, DD, DD, 0, 1.f, 0, 0, 512, 9, (size_t)DD * 512);
  gemm_bt<EPI_BF16S><<<g4(8192, 512), blk, 0, stream>>>(R6 /*CQ*/, CK, nullptr, Sc, nullptr,
      48, DD, DD, 512, scl, 12, (size_t)512 * DD, 0, 0, 0);
  softmax_bf16<512><<<8192, blk, 0, stream>>>(Sc);
  gemm8<EPI_BF16><<<g8(8192, DD), blk8, 0, stream>>>(Sc, CVt, nullptr, R4 + 1536, nullptr,
      8, 512, 512, 3072, 1.f, 12, (size_t)DD * 512, 0, 0, 0);

  // merged out = x + concat @ [Wo;CWo] + (bo+Cbo)
  T(Wo, R1, DD, DD, nullptr, 3072);
  T(CWo, R1 + 1536, DD, DD, nullptr, 3072);
  gemm8<EPI_ADD_X><<<g8(8192, DD), blk8, 0, stream>>>(R4, R1, biasm, out, x,
      48, 3072, 3072, DD, 1.f, 0, 0, 0, 0, 0);

  // FFN: LN -> W1+gelu (single N=6144) -> W2 (single K=6144) acc
  norm_ln<<<8192, blk, 0, stream>>>(x, lnw, lnb, R2);
  T(W1, R0, DD, FF, nullptr, DD);
  gemm8<EPI_GELU><<<g8(8192, FF), blk8, 0, stream>>>(R2, R0, b1, H, nullptr,
      24, DD, DD, FF, 1.f, 0, 0, 0, 0, 0);
  T(W2, R1, FF, DD, nullptr, FF);
  gemm8<EPI_ACC><<<g8(8192, DD), blk8, 0, stream>>>(H, R1, b2, out, nullptr,
      96, FF, FF, DD, 1.f, 0, 0, 0, 0, 0);
}

// Round 15
// 1100.731 us; speedup vs baseline: 1.8112x; 1.0226x over previous
//
#include <hip/hip_runtime.h>
#include <hip/hip_bf16.h>
#include <cmath>

#define DD 1536
#define FF 6144

typedef __bf16 bf16_t;
typedef __bf16 bf16x8 __attribute__((ext_vector_type(8)));
typedef __bf16 bf16x4 __attribute__((ext_vector_type(4)));
typedef float  f32x4  __attribute__((ext_vector_type(4)));

#define VM0 asm volatile("s_waitcnt vmcnt(0)" ::: "memory")
#define SB  __builtin_amdgcn_sched_barrier(0)
#define LGKM_0 do { asm volatile("s_waitcnt lgkmcnt(0)" :::); SB; } while (0)
#define LGKM_4 do { asm volatile("s_waitcnt lgkmcnt(4)" :::); SB; } while (0)
#define BAR __builtin_amdgcn_s_barrier()

__device__ __forceinline__ void async_load16(const bf16_t* g, bf16_t* l) {
  __builtin_amdgcn_global_load_lds(
      (const __attribute__((address_space(1))) void*)g,
      (__attribute__((address_space(3))) void*)l, 16, 0, 0);
}

// inline-asm LDS read: NOT ordered vs global_load_lds by the compiler; ordering is
// done explicitly via {vmcnt; barrier} (RAW) and counted lgkmcnt + sched_barrier (use).
__device__ __forceinline__ bf16x8 ds_read128(unsigned int addr) {
  bf16x8 r;
  asm volatile("ds_read_b128 %0, %1" : "=v"(r) : "v"(addr));
  return r;
}

// bijective XCD-aware remap (m204)
__device__ __forceinline__ void xcd_remap(int& bx, int& by) {
  const int gx = gridDim.x, gy = gridDim.y;
  int wg = by * gx + bx;
  const int nwg = gx * gy;
  const int q = nwg >> 3, r = nwg & 7, xcd = wg & 7, o = wg >> 3;
  wg = (xcd < r ? xcd * (q + 1) : r * (q + 1) + (xcd - r) * q) + o;
  bx = wg % gx;
  by = wg / gx;
}

// ---------------- weight fp32 -> bf16 transpose; optional per-K scale; output row stride ldt
__global__ __launch_bounds__(256) void transpose_to_bf16(
    const float* __restrict__ W, bf16_t* __restrict__ Wt, int K, int N,
    const float* __restrict__ s, int ldt) {
  __shared__ float tile[32][33];
  const int tx = threadIdx.x, ty = threadIdx.y;  // 32 x 8
  const int n0 = blockIdx.x * 32, k0 = blockIdx.y * 32;
#pragma unroll
  for (int i = 0; i < 4; i++)
    tile[ty + 8 * i][tx] = W[(size_t)(k0 + ty + 8 * i) * N + n0 + tx];
  __syncthreads();
  const float sc = (s != nullptr) ? s[k0 + tx] : 1.f;
#pragma unroll
  for (int i = 0; i < 4; i++)
    Wt[(size_t)(n0 + ty + 8 * i) * ldt + k0 + tx] = (bf16_t)(tile[tx][ty + 8 * i] * sc);
}

// ---------------- biasm = a + b ----------------
__global__ __launch_bounds__(256) void bias_add2(
    const float* __restrict__ a, const float* __restrict__ b, float* __restrict__ o, int n) {
  const int i = blockIdx.x * 256 + threadIdx.x;
  if (i < n) o[i] = a[i] + b[i];
}

// ---------------- reduction helpers ----------------
__device__ __forceinline__ void breduce1(float& a) {
#pragma unroll
  for (int off = 32; off; off >>= 1) a += __shfl_xor(a, off);
  __shared__ float sa[4];
  const int w = threadIdx.x >> 6, ln = threadIdx.x & 63;
  if (ln == 0) sa[w] = a;
  __syncthreads();
  a = (sa[0] + sa[1]) + (sa[2] + sa[3]);
  __syncthreads();
}

__device__ __forceinline__ void breduce2(float& a, float& b) {
#pragma unroll
  for (int off = 32; off; off >>= 1) {
    a += __shfl_xor(a, off);
    b += __shfl_xor(b, off);
  }
  __shared__ float sa[4], sb[4];
  const int w = threadIdx.x >> 6, ln = threadIdx.x & 63;
  if (ln == 0) { sa[w] = a; sb[w] = b; }
  __syncthreads();
  a = (sa[0] + sa[1]) + (sa[2] + sa[3]);
  b = (sb[0] + sb[1]) + (sb[2] + sb[3]);
  __syncthreads();
}

// ---------------- x: xr = x*rq (bf16) + rqinv[row] = sqrt(ms+eps) ----------------
__global__ __launch_bounds__(256) void norm_x1(
    const float* __restrict__ x, bf16_t* __restrict__ xr, float* __restrict__ rqinv) {
  const int row = blockIdx.x, t = threadIdx.x;
  const float* p = x + (size_t)row * DD;
  f32x4 v0 = ((const f32x4*)p)[t];
  f32x4 v1 = 0.0f;
  if (t < 128) v1 = ((const f32x4*)p)[256 + t];
  float s2 = 0.f;
#pragma unroll
  for (int e = 0; e < 4; e++) s2 += v0[e] * v0[e];
  if (t < 128) {
#pragma unroll
    for (int e = 0; e < 4; e++) s2 += v1[e] * v1[e];
  }
  breduce1(s2);
  const float ms = s2 * (1.f / DD) + 1e-7f;
  const float rq = rsqrtf(ms);
  if (t == 0) rqinv[row] = sqrtf(ms);
  auto emit = [&](int ci, f32x4 v) {
    bf16x4 orr;
#pragma unroll
    for (int e = 0; e < 4; e++) orr[e] = (bf16_t)(v[e] * rq);
    *(bf16x4*)(xr + (size_t)row * DD + ci * 4) = orr;
  };
  emit(t, v0);
  if (t < 128) emit(256 + t, v1);
}

// ---------------- LayerNorm -> bf16 ----------------
__global__ __launch_bounds__(256) void norm_ln(
    const float* __restrict__ x, const float* __restrict__ w,
    const float* __restrict__ bb, bf16_t* __restrict__ o) {
  const int row = blockIdx.x, t = threadIdx.x;
  const float* p = x + (size_t)row * DD;
  f32x4 v0 = ((const f32x4*)p)[t];
  f32x4 v1 = 0.0f;
  if (t < 128) v1 = ((const f32x4*)p)[256 + t];
  float s = 0.f, s2 = 0.f;
#pragma unroll
  for (int e = 0; e < 4; e++) { s += v0[e]; s2 += v0[e] * v0[e]; }
  if (t < 128) {
#pragma unroll
    for (int e = 0; e < 4; e++) { s += v1[e]; s2 += v1[e] * v1[e]; }
  }
  breduce2(s, s2);
  const float mu = s * (1.f / DD);
  const float rln = rsqrtf(s2 * (1.f / DD) - mu * mu + 1e-5f);
  auto emit = [&](int ci, f32x4 v) {
    const int i0 = ci * 4;
    bf16x4 ov;
#pragma unroll
    for (int e = 0; e < 4; e++)
      ov[e] = (bf16_t)((v[e] - mu) * rln * w[i0 + e] + bb[i0 + e]);
    *(bf16x4*)(o + (size_t)row * DD + i0) = ov;
  };
  emit(t, v0);
  if (t < 128) emit(256 + t, v1);
}

// ---------------- text: Tb = raw bf16, Tck = text*rtq ----------
__global__ __launch_bounds__(256) void norm_t2(
    const float* __restrict__ te, bf16_t* __restrict__ tb, bf16_t* __restrict__ tck) {
  const int row = blockIdx.x, t = threadIdx.x;
  const float* p = te + (size_t)row * DD;
  f32x4 v0 = ((const f32x4*)p)[t];
  f32x4 v1 = 0.0f;
  if (t < 128) v1 = ((const f32x4*)p)[256 + t];
  float s2 = 0.f;
#pragma unroll
  for (int e = 0; e < 4; e++) s2 += v0[e] * v0[e];
  if (t < 128) {
#pragma unroll
    for (int e = 0; e < 4; e++) s2 += v1[e] * v1[e];
  }
  breduce1(s2);
  const float rq = rsqrtf(s2 * (1.f / DD) + 1e-7f);
  auto emit = [&](int ci, f32x4 v) {
    bf16x4 ob, oc;
#pragma unroll
    for (int e = 0; e < 4; e++) {
      ob[e] = (bf16_t)v[e];
      oc[e] = (bf16_t)(v[e] * rq);
    }
    const size_t o = (size_t)row * DD + ci * 4;
    *(bf16x4*)(tb + o) = ob;
    *(bf16x4*)(tck + o) = oc;
  };
  emit(t, v0);
  if (t < 128) emit(256 + t, v1);
}

// ---------------- in-place bf16 row softmax ----------------
template <int NC>
__global__ __launch_bounds__(256) void softmax_bf16(bf16_t* __restrict__ S) {
  const int t = threadIdx.x;
  bf16_t* sr = S + (size_t)blockIdx.x * NC;
  constexpr int NV = (NC / 8 + 255) / 256;
  float v[NV][8];
  float mx = -3.4e38f;
#pragma unroll
  for (int i = 0; i < NV; i++) {
    const int idx = t + i * 256;
    if (idx * 8 < NC) {
      bf16x8 b = ((const bf16x8*)sr)[idx];
#pragma unroll
      for (int e = 0; e < 8; e++) {
        v[i][e] = (float)b[e];
        mx = fmaxf(mx, v[i][e]);
      }
    }
  }
#pragma unroll
  for (int off = 32; off; off >>= 1) mx = fmaxf(mx, __shfl_xor(mx, off));
  __shared__ float sm[4];
  const int w = t >> 6, ln = t & 63;
  if (ln == 0) sm[w] = mx;
  __syncthreads();
  mx = fmaxf(fmaxf(sm[0], sm[1]), fmaxf(sm[2], sm[3]));
  __syncthreads();
  float sum = 0.f;
#pragma unroll
  for (int i = 0; i < NV; i++) {
    const int idx = t + i * 256;
    if (idx * 8 < NC) {
#pragma unroll
      for (int e = 0; e < 8; e++) {
        v[i][e] = __expf(v[i][e] - mx);
        sum += v[i][e];
      }
    }
  }
#pragma unroll
  for (int off = 32; off; off >>= 1) sum += __shfl_xor(sum, off);
  __shared__ float ss[4];
  if (ln == 0) ss[w] = sum;
  __syncthreads();
  sum = (ss[0] + ss[1]) + (ss[2] + ss[3]);
  const float inv = 1.f / sum;
#pragma unroll
  for (int i = 0; i < NV; i++) {
    const int idx = t + i * 256;
    if (idx * 8 < NC) {
      bf16x8 o;
#pragma unroll
      for (int e = 0; e < 8; e++) o[e] = (bf16_t)(v[i][e] * inv);
      ((bf16x8*)sr)[idx] = o;
    }
  }
}

enum { EPI_BF16 = 0, EPI_F32_SCALE = 1, EPI_ADD_X = 2, EPI_ACC = 3, EPI_GELU = 4, EPI_TRANS = 5, EPI_BF16S = 6, EPI_PROJ3 = 7 };

template <int EPI>
__device__ __forceinline__ void epi_frag(
    f32x4 v, int r0, int c, const float* bias, void* Cout, const float* Xres,
    int ldc, float scale, int t_ld, int t_bshift, size_t t_bstride) {
  const float bv = (bias != nullptr) ? bias[c] : 0.f;
  if constexpr (EPI == EPI_BF16) {
    bf16_t* C = (bf16_t*)Cout;
#pragma unroll
    for (int r = 0; r < 4; r++) C[(size_t)(r0 + r) * ldc + c] = (bf16_t)(v[r] + bv);
  } else if constexpr (EPI == EPI_F32_SCALE) {
    float* C = (float*)Cout;
#pragma unroll
    for (int r = 0; r < 4; r++) C[(size_t)(r0 + r) * ldc + c] = v[r] * scale;
  } else if constexpr (EPI == EPI_BF16S) {
    bf16_t* C = (bf16_t*)Cout;
#pragma unroll
    for (int r = 0; r < 4; r++) C[(size_t)(r0 + r) * ldc + c] = (bf16_t)(v[r] * scale);
  } else if constexpr (EPI == EPI_ADD_X) {
    float* C = (float*)Cout;
#pragma unroll
    for (int r = 0; r < 4; r++) {
      const size_t ix = (size_t)(r0 + r) * ldc + c;
      C[ix] = Xres[ix] + v[r] + bv;
    }
  } else if constexpr (EPI == EPI_ACC) {
    float* C = (float*)Cout;
#pragma unroll
    for (int r = 0; r < 4; r++) {
      const size_t ix = (size_t)(r0 + r) * ldc + c;
      C[ix] += v[r] + bv;
    }
  } else if constexpr (EPI == EPI_GELU) {
    bf16_t* C = (bf16_t*)Cout;
#pragma unroll
    for (int r = 0; r < 4; r++) {
      const float h = v[r] + bv;
      C[(size_t)(r0 + r) * ldc + c] = (bf16_t)(0.5f * h * (1.f + erff(h * 0.70710678118654752f)));
    }
  } else if constexpr (EPI == EPI_TRANS) {  // batched C^T: out[b][c][n]
    const int b = r0 >> t_bshift;
    const int n = r0 & ((1 << t_bshift) - 1);
    bf16_t* C = (bf16_t*)Cout + (size_t)b * t_bstride + (size_t)c * t_ld + n;
    bf16x4 o;
#pragma unroll
    for (int r = 0; r < 4; r++) o[r] = (bf16_t)(v[r] + bv);
    *(bf16x4*)C = o;
  } else {  // EPI_PROJ3: mega-projection. Cout=R4 (QK base, ldc 3072); arena-contiguous
            // Vt = Cout+25165824 (V^T batched, ld 4096), CQ = Cout+37748736 (ldc 1536).
            // Xres = rqinv[row] (per-row inverse rms factor, applied to V region only).
    bf16_t* base = (bf16_t*)Cout;
    if (c < 1536) {          // V^T with per-row descale
      const int b = r0 >> 12, n = r0 & 4095;
      bf16_t* C = base + 25165824 + (size_t)b * ((size_t)DD * 4096) + (size_t)c * 4096 + n;
      bf16x4 o;
#pragma unroll
      for (int r = 0; r < 4; r++) o[r] = (bf16_t)(v[r] * Xres[r0 + r] + bv);
      *(bf16x4*)C = o;
    } else if (c < 4608) {   // Q|K row-major, ldc 3072
#pragma unroll
      for (int r = 0; r < 4; r++) base[(size_t)(r0 + r) * 3072 + (c - 1536)] = (bf16_t)(v[r] + bv);
    } else {                 // CQ row-major, ldc 1536
      bf16_t* C = base + 37748736;
#pragma unroll
      for (int r = 0; r < 4; r++) C[(size_t)(r0 + r) * 1536 + (c - 4608)] = (bf16_t)(v[r] + bv);
    }
  }
}

// ---------------- gemm_bt: 128x128 tile, 4 waves, BK=32 (proven r2 kernel + batch-B) ------
template <int EPI>
__global__ __launch_bounds__(256) void gemm_bt(
    const bf16_t* __restrict__ A, const bf16_t* __restrict__ B,
    const float* __restrict__ bias, void* __restrict__ Cout,
    const float* __restrict__ Xres,
    int nK, int lda, int ldb, int ldc, float scale,
    int bsh, size_t bstr, int t_ld, int t_bshift, size_t t_bstride) {
  __shared__ __align__(16) bf16_t As[2][128 * 32];
  __shared__ __align__(16) bf16_t Bs[2][128 * 32];
  const int tid = threadIdx.x;
  int bx = blockIdx.x, by = blockIdx.y;
  xcd_remap(bx, by);
  const int m0 = by * 128, n0 = bx * 128;
  const int wave = tid >> 6, lane = tid & 63, l15 = lane & 15, hi = lane >> 4;
  const int wm = wave >> 1, wn = wave & 1;
  const int srow = tid >> 2, scol = (tid & 3) << 3;

  const bf16_t* Bb = bsh ? (B + (size_t)(m0 >> bsh) * bstr) : B;
  const bf16_t* ga = A + (size_t)(m0 + srow) * lda + scol;
  const bf16_t* gb = Bb + (size_t)(n0 + srow) * ldb + scol;
  const int lo = wave * 512;

  f32x4 acc[4][4];
#pragma unroll
  for (int i = 0; i < 4; i++)
#pragma unroll
    for (int j = 0; j < 4; j++) acc[i][j] = 0.0f;

  auto stage = [&](int buf, int kt) {
    const bf16_t* a = ga + (size_t)kt * 32;
    const bf16_t* b = gb + (size_t)kt * 32;
    async_load16(a, &As[buf][lo]);
    async_load16(a + (size_t)64 * lda, &As[buf][2048 + lo]);
    async_load16(b, &Bs[buf][lo]);
    async_load16(b + (size_t)64 * ldb, &Bs[buf][2048 + lo]);
  };

  auto compute = [&](int buf) {
    bf16x8 af[4], bg[4];
#pragma unroll
    for (int i = 0; i < 4; i++)
      af[i] = *(const bf16x8*)&As[buf][(wm * 64 + i * 16 + l15) * 32 + hi * 8];
#pragma unroll
    for (int j = 0; j < 4; j++)
      bg[j] = *(const bf16x8*)&Bs[buf][(wn * 64 + j * 16 + l15) * 32 + hi * 8];
#pragma unroll
    for (int i = 0; i < 4; i++)
#pragma unroll
      for (int j = 0; j < 4; j++)
        acc[i][j] = __builtin_amdgcn_mfma_f32_16x16x32_bf16(af[i], bg[j], acc[i][j], 0, 0, 0);
  };

  stage(0, 0);
  __syncthreads();
  for (int kt = 0; kt < nK; ++kt) {
    if (kt + 1 < nK) stage((kt + 1) & 1, kt + 1);
    compute(kt & 1);
    __syncthreads();
  }

#pragma unroll
  for (int i = 0; i < 4; i++) {
    const int r0 = m0 + wm * 64 + i * 16 + hi * 4;
#pragma unroll
    for (int j = 0; j < 4; j++) {
      const int c = n0 + wn * 64 + j * 16 + l15;
      epi_frag<EPI>(acc[i][j], r0, c, bias, Cout, Xres, ldc, scale, t_ld, t_bshift, t_bstride);
    }
  }
}

// ---------------- gemm8: 256x256, 8 waves, BK=64, single-barrier K-tile (r14 fixed) -------
// Schedule: {VM0; BAR; stage tile k+1 -> buf^1; issue af0(8)+bg0(4)+bg1(4); lgkm(4) ->
// MM(0,0); lgkm(0) -> MM(0,1); re-issue LDA(buf,1) into af (consumers MM(0,0)/MM(0,1)
// already issued - same overwrite pattern r13 ran); lgkm(0) -> MM(1,0); MM(1,1)}.
// One barrier + one vmcnt per K-tile; waves free-run the body (m114 pipe overlap).
// r14 NaN root cause fixed: MM(0,0) no longer consumes af overwritten by LDA(buf,1).
// RAW: per-wave VM0 drains own tile-k DMA (issued last iter, full body in flight);
// BAR globalizes (r6). WAR: every wave's prev-iter ds_reads drained at its final
// lgkm(0) before entering BAR -> staging buf^1 after BAR is safe. Registers: af[4][2]
// + bg[2][2][2] = 64 VGPR, identical to r13 (no spill; r10 lesson).
// lgkm FIFO ledger (DS-only): issue af0(8), bg0(4), bg1(4) = 16. lgkm(4): oldest 12
// = af0+bg0 done. lgkm(0): bg1 done. After LDA(buf,1)=8: lgkm(0): af1 done.
template <int EPI>
__global__ __launch_bounds__(512, 2) void gemm8(
    const bf16_t* __restrict__ A, const bf16_t* __restrict__ B,
    const float* __restrict__ bias, void* __restrict__ Cout,
    const float* __restrict__ Xres,
    int nT, int lda, int ldb, int ldc, float scale,
    int bsh, size_t bstr, int t_ld, int t_bshift, size_t t_bstride) {
  __shared__ __align__(16) bf16_t As[2][256 * 64];
  __shared__ __align__(16) bf16_t Bs[2][256 * 64];
  const int tid = threadIdx.x;
  int bx = blockIdx.x, by = blockIdx.y;
  xcd_remap(bx, by);
  const int m0 = by * 256, n0 = bx * 256;
  const int wave = tid >> 6, lane = tid & 63, l15 = lane & 15, hi = lane >> 4;
  const int wm = wave >> 2, wn = wave & 3;  // 2 x 4 waves; per-wave 128x64 output

  const int srow = tid >> 3;
  const int scol = ((tid & 7) ^ (srow & 7)) << 3;
  const bf16_t* Bb = bsh ? (B + (size_t)(m0 >> bsh) * bstr) : B;
  const bf16_t* gA = A + (size_t)(m0 + srow) * lda + scol;
  const bf16_t* gB = Bb + (size_t)(n0 + srow) * ldb + scol;
  const int ldst = wave * 512;

  // per-lane ds_read byte bases (buf 0); buf1 = +32768
  const unsigned swz0 = (unsigned)(((hi ^ (l15 & 7)) << 3) * 2);
  const unsigned swz1 = (unsigned)((((hi + 4) ^ (l15 & 7)) << 3) * 2);
  const unsigned aBase = (unsigned)(size_t)&As[0][0] + (unsigned)((wm * 128 + l15) * 128);
  const unsigned bBase = (unsigned)(size_t)&Bs[0][0] + (unsigned)((wn * 64 + l15) * 128);
  const unsigned a0 = aBase + swz0, a1 = aBase + swz1;
  const unsigned b0 = bBase + swz0, b1 = bBase + swz1;

  f32x4 acc[8][4];
#pragma unroll
  for (int i = 0; i < 8; i++)
#pragma unroll
    for (int j = 0; j < 4; j++) acc[i][j] = 0.0f;

  auto stgA = [&](int t, int half) {
    if (t >= nT) return;
    const int buf = t & 1, r0 = half << 7;
    const size_t kof = (size_t)t * 64;
    async_load16(gA + (size_t)r0 * lda + kof, &As[buf][r0 * 64 + ldst]);
    async_load16(gA + (size_t)(r0 + 64) * lda + kof, &As[buf][(r0 + 64) * 64 + ldst]);
  };
  auto stgB = [&](int t, int half) {
    if (t >= nT) return;
    const int buf = t & 1, r0 = half << 7;
    const size_t kof = (size_t)t * 64;
    async_load16(gB + (size_t)r0 * ldb + kof, &Bs[buf][r0 * 64 + ldst]);
    async_load16(gB + (size_t)(r0 + 64) * ldb + kof, &Bs[buf][(r0 + 64) * 64 + ldst]);
  };

  bf16x8 af[4][2], bg[2][2][2];
  auto LDA = [&](int buf, int mh) {
#pragma unroll
    for (int i = 0; i < 4; i++) {
      const unsigned d = (unsigned)(buf * 32768 + (mh * 4 + i) * 2048);
      af[i][0] = ds_read128(a0 + d);
      af[i][1] = ds_read128(a1 + d);
    }
  };
  auto LDB = [&](int buf, int nh) {
#pragma unroll
    for (int j = 0; j < 2; j++) {
      const unsigned d = (unsigned)(buf * 32768 + (nh * 2 + j) * 2048);
      bg[nh][j][0] = ds_read128(b0 + d);
      bg[nh][j][1] = ds_read128(b1 + d);
    }
  };
  auto MM = [&](int mh, int nh) {
    __builtin_amdgcn_s_setprio(1);
#pragma unroll
    for (int i = 0; i < 4; i++)
#pragma unroll
      for (int j = 0; j < 2; j++)
#pragma unroll
        for (int ks = 0; ks < 2; ks++)
          acc[mh * 4 + i][nh * 2 + j] = __builtin_amdgcn_mfma_f32_16x16x32_bf16(
              af[i][ks], bg[nh][j][ks], acc[mh * 4 + i][nh * 2 + j], 0, 0, 0);
    __builtin_amdgcn_s_setprio(0);
  };

  // one K-tile iteration; buf is a compile-time literal at each call site
  auto iter = [&](int k, int buf) {
    VM0;   // per-wave: own tile-k loads (issued last iter) drained
    BAR;   // globalize drain (RAW) + all waves' buf^1 reads done (WAR)
    // stage all 4 halves of tile k+1 into buf^1 (full body covers HBM latency)
    stgB(k + 1, 0);
    stgB(k + 1, 1);
    stgA(k + 1, 0);
    stgA(k + 1, 1);
    // issue 16 reads of tile k: af0(8), bg0(4), bg1(4)
    LDA(buf, 0);
    LDB(buf, 0);
    LDB(buf, 1);
    SB;
    LGKM_4;   // af0+bg0 ready (oldest 12 of 16)
    MM(0, 0);
    LGKM_0;   // bg1 ready
    MM(0, 1);
    // re-issue af <- mh1 (consumers of af0 already issued)
    LDA(buf, 1);
    SB;
    LGKM_0;   // af1 ready
    MM(1, 0);
    MM(1, 1);
  };

  // prologue: stage tile 0 (4 halves)
  stgB(0, 0); stgB(0, 1); stgA(0, 0); stgA(0, 1);

  for (int k = 0; k < nT; k += 2) {  // nT is even for all call sites
    iter(k, 0);
    iter(k + 1, 1);
  }

#pragma unroll
  for (int fi = 0; fi < 8; fi++) {
    const int r0 = m0 + wm * 128 + fi * 16 + hi * 4;
#pragma unroll
    for (int fj = 0; fj < 4; fj++) {
      const int c = n0 + wn * 64 + fj * 16 + l15;
      epi_frag<EPI>(acc[fi][fj], r0, c, bias, Cout, Xres, ldc, scale, t_ld, t_bshift, t_bstride);
    }
  }
}

// ---------------- host ----------------
extern "C" void kernel_launch(void* const* d_in, const int* in_sizes, int n_in,
                              void* d_out, int out_size, void* d_ws, size_t ws_size,
                              hipStream_t stream) {
  (void)in_sizes; (void)n_in; (void)out_size; (void)ws_size;
  const float* x   = (const float*)d_in[0];
  const float* te  = (const float*)d_in[1];
  const float* sqw = (const float*)d_in[2];
  const float* skw = (const float*)d_in[3];
  const float* cqw = (const float*)d_in[4];
  const float* ckw = (const float*)d_in[5];
  const float* lnw = (const float*)d_in[6];
  const float* lnb = (const float*)d_in[7];
  const float* Wq = (const float*)d_in[8];  const float* bq = (const float*)d_in[9];
  const float* Wk = (const float*)d_in[10]; const float* bk = (const float*)d_in[11];
  const float* Wv = (const float*)d_in[12]; const float* bv = (const float*)d_in[13];
  const float* Wo = (const float*)d_in[14]; const float* bo = (const float*)d_in[15];
  const float* CWq = (const float*)d_in[16]; const float* Cbq = (const float*)d_in[17];
  const float* CWk = (const float*)d_in[18]; const float* Cbk = (const float*)d_in[19];
  const float* CWv = (const float*)d_in[20]; const float* Cbv = (const float*)d_in[21];
  const float* CWo = (const float*)d_in[22]; const float* Cbo = (const float*)d_in[23];
  const float* W1 = (const float*)d_in[24]; const float* b1 = (const float*)d_in[25];
  const float* W2 = (const float*)d_in[26]; const float* b2 = (const float*)d_in[27];
  float* out = (float*)d_out;

  // ---- arena (bf16 el offsets); peak ~170 MB ----
  bf16_t* ws = (bf16_t*)d_ws;
  bf16_t* R0 = ws;                  // 9437184: [Wv|Wq|Wk|CWq]^T -> {CK,CVt,Sc} -> W1^T
  bf16_t* R1 = ws + 9437184;        // 9437184: CWk/CWv^T -> [Wo|CWo]^T -> W2^T
  bf16_t* R2 = ws + 18874368;       // 12582912: xr -> LNo
  bf16_t* Tb  = ws + 31457280;      // 1572864
  bf16_t* Tck = ws + 33030144;      // 1572864
  bf16_t* R4 = ws + 34603008;       // 25165824: Q|K(ldc3072) -> concat APre|CPre -> H[0:..]
  bf16_t* R5 = ws + 59768832;       // 12582912: V^T -> H mid   (= R4 + 25165824)
  bf16_t* R6 = ws + 72351744;       // 12582912: CQ -> H end    (= R4 + 37748736)
  bf16_t* S  = ws;                  // 33554432 overlay (self-attn scores)
  float* bcat4 = (float*)(ws + 84934656);    // 6144 f32 = [bv|bq|bk|Cbq]
  float* biasm = (float*)(ws + 84946944);    // 1536 f32 = bo+Cbo
  float* rqinv = (float*)(ws + 84950016);    // 8192 f32
  bf16_t* CK  = R0;
  bf16_t* CVt = R0 + 1572864;
  bf16_t* Sc  = R0 + 3145728;       // 8192x512 bf16
  bf16_t* H   = R4;                 // 8192x6144 (R4+R5+R6 contiguous)

  const dim3 blk(256), blk8(512), tb(32, 8);
  const float scl = 0.025515518153991442f;  // 1/sqrt(1536)

  auto T = [&](const float* W, bf16_t* Wt, int K, int N, const float* s, int ldt) {
    transpose_to_bf16<<<dim3(N / 32, K / 32), tb, 0, stream>>>(W, Wt, K, N, s, ldt);
  };
  auto g8 = [](int M, int N) { return dim3(N / 256, M / 256); };
  auto g4 = [](int M, int N) { return dim3(N / 128, M / 128); };

  // biases
  hipMemcpyAsync(bcat4,        bv,  DD * sizeof(float), hipMemcpyDeviceToDevice, stream);
  hipMemcpyAsync(bcat4 + DD,   bq,  DD * sizeof(float), hipMemcpyDeviceToDevice, stream);
  hipMemcpyAsync(bcat4 + 2*DD, bk,  DD * sizeof(float), hipMemcpyDeviceToDevice, stream);
  hipMemcpyAsync(bcat4 + 3*DD, Cbq, DD * sizeof(float), hipMemcpyDeviceToDevice, stream);
  bias_add2<<<6, blk, 0, stream>>>(bo, Cbo, biasm, DD);

  // norm: xr + per-row descale
  norm_x1<<<8192, blk, 0, stream>>>(x, R2, rqinv);

  // mega-projection: [V^T | Q|K | CQ] = xr @ [Wv | Wq*sqw | Wk*skw | CWq*cqw]^T, N=6144
  T(Wv,  R0,               DD, DD, nullptr, DD);
  T(Wq,  R0 + 2359296,     DD, DD, sqw,     DD);
  T(Wk,  R0 + 4718592,     DD, DD, skw,     DD);
  T(CWq, R0 + 7077888,     DD, DD, cqw,     DD);
  gemm8<EPI_PROJ3><<<g8(8192, FF), blk8, 0, stream>>>(R2, R0, bcat4, R4, rqinv,
      24, DD, DD, 3072, 1.f, 0, 0, 0, 0, 0);

  // self-attention (batched over 2 via m0>>12)
  gemm8<EPI_BF16S><<<g8(8192, 4096), blk8, 0, stream>>>(R4 /*Q*/, R4 + DD /*K*/, nullptr, S, nullptr,
      24, 3072, 3072, 4096, scl, 12, (size_t)4096 * 3072, 0, 0, 0);
  softmax_bf16<4096><<<8192, blk, 0, stream>>>(S);
  gemm8<EPI_BF16><<<g8(8192, DD), blk8, 0, stream>>>(S, R5, nullptr, R4, nullptr,
      64, 4096, 4096, 3072, 1.f, 12, (size_t)DD * 4096, 0, 0, 0);

  // cross-attention
  norm_t2<<<1024, blk, 0, stream>>>(te, Tb, Tck);
  T(CWk, R1, DD, DD, ckw, DD);
  gemm_bt<EPI_BF16><<<g4(1024, DD), blk, 0, stream>>>(Tck, R1, Cbk, CK, nullptr,
      48, DD, DD, DD, 1.f, 0, 0, 0, 0, 0);
  T(CWv, R1 + 2359296, DD, DD, nullptr, DD);
  gemm_bt<EPI_TRANS><<<g4(1024, DD), blk, 0, stream>>>(Tb, R1 + 2359296, Cbv, CVt, nullptr,
      48, DD, DD, 0, 1.f, 0, 0, 512, 9, (size_t)DD * 512);
  gemm_bt<EPI_BF16S><<<g4(8192, 512), blk, 0, stream>>>(R6 /*CQ*/, CK, nullptr, Sc, nullptr,
      48, DD, DD, 512, scl, 12, (size_t)512 * DD, 0, 0, 0);
  softmax_bf16<512><<<8192, blk, 0, stream>>>(Sc);
  gemm8<EPI_BF16><<<g8(8192, DD), blk8, 0, stream>>>(Sc, CVt, nullptr, R4 + 1536, nullptr,
      8, 512, 512, 3072, 1.f, 12, (size_t)DD * 512, 0, 0, 0);

  // merged out = x + concat @ [Wo;CWo] + (bo+Cbo)
  T(Wo, R1, DD, DD, nullptr, 3072);
  T(CWo, R1 + 1536, DD, DD, nullptr, 3072);
  gemm8<EPI_ADD_X><<<g8(8192, DD), blk8, 0, stream>>>(R4, R1, biasm, out, x,
      48, 3072, 3072, DD, 1.f, 0, 0, 0, 0, 0);

  // FFN: LN -> W1+gelu (single N=6144) -> W2 (single K=6144) acc
  norm_ln<<<8192, blk, 0, stream>>>(x, lnw, lnb, R2);
  T(W1, R0, DD, FF, nullptr, DD);
  gemm8<EPI_GELU><<<g8(8192, FF), blk8, 0, stream>>>(R2, R0, b1, H, nullptr,
      24, DD, DD, FF, 1.f, 0, 0, 0, 0, 0);
  T(W2, R1, FF, DD, nullptr, FF);
  gemm8<EPI_ACC><<<g8(8192, DD), blk8, 0, stream>>>(H, R1, b2, out, nullptr,
      96, FF, FF, DD, 1.f, 0, 0, 0, 0, 0);
}